// Round 3
// baseline (189.866 us; speedup 1.0000x reference)
//
#include <hip/hip_runtime.h>
#include <hip/hip_bf16.h>
#include <math.h>

#define B_ 8
#define T_ 2048
#define E_ 1024
#define H_ 128
#define M_ (B_*T_)              // 16384
#define SCALE_ 45.25483399593904f   // sqrt(2048) per reference
#define SEG_ 4                      // key-range split factor for attention

typedef __attribute__((ext_vector_type(8))) short bf16x8;
typedef __attribute__((ext_vector_type(4))) short bf16x4;
typedef __attribute__((ext_vector_type(4))) float f32x4;

#define mfma16(A, Bv, C) __builtin_amdgcn_mfma_f32_16x16x32_bf16((A), (Bv), (C), 0, 0, 0)

// ---- fragment-order flat indices (ushort elements) -------------------------
// lane = quad*16 + l15 throughout.
// W-frag (proj B operand): g = mat*8+nt (0..23), kc = k/32 (0..31);
//   element (n = (g&7)*16 + l15, k = kc*32 + quad*8 + j)
#define FRAGW(g, kc, lane)  ((((size_t)(g)*32 + (kc))*64 + (lane))*8)
// K-frag (attn QK B operand): kt16 = key/16 (0..127), kc = h/32 (0..3);
//   element (key = kt16*16 + l15, h = kc*32 + quad*8 + j)
#define FRAGK(b, kt16, kc, lane) (((((size_t)(b)*128 + (kt16))*4 + (kc))*64 + (lane))*8)
// V-frag (attn PV B operand): ht = h/16 (0..7), kt32 = key/32 (0..63);
//   element (h = ht*16 + l15, key = kt32*32 + quad*8 + j)
#define FRAGV(b, ht, kt32, lane) (((((size_t)(b)*8 + (ht))*64 + (kt32))*64 + (lane))*8)

__device__ __forceinline__ ushort bf16_rne(float f) {
  unsigned u = __float_as_uint(f);
  u += 0x7fffu + ((u >> 16) & 1u);
  return (ushort)(u >> 16);
}
__device__ __forceinline__ float bf16_tof(ushort h) {
  return __uint_as_float(((unsigned)h) << 16);
}

// LDS-only barrier: drain DS ops (cross-wave LDS dependency) but leave
// register-destined global prefetches (vmcnt) in flight across the barrier.
__device__ __forceinline__ void lds_barrier() {
  asm volatile("s_waitcnt lgkmcnt(0)" ::: "memory");
  __builtin_amdgcn_s_barrier();
}

// DPP row_ror:N within 16-lane rows; rotate-reduce leaves result in all lanes.
template <int N>
__device__ __forceinline__ float ror16(float x) {
  return __uint_as_float((unsigned)__builtin_amdgcn_update_dpp(
      0, (int)__float_as_uint(x), 0x120 + N, 0xF, 0xF, true));
}
__device__ __forceinline__ float rowmax16(float x) {
  x = fmaxf(x, ror16<8>(x));
  x = fmaxf(x, ror16<4>(x));
  x = fmaxf(x, ror16<2>(x));
  x = fmaxf(x, ror16<1>(x));
  return x;
}
__device__ __forceinline__ float rowsum16(float x) {
  x += ror16<8>(x);
  x += ror16<4>(x);
  x += ror16<2>(x);
  x += ror16<1>(x);
  return x;
}

// ---------------------------------------------------------------------------
// Kernel 0: split W -> whT/wlT bf16 in PROJ-B FRAGMENT ORDER. (unchanged)
// ---------------------------------------------------------------------------
__global__ __launch_bounds__(256) void wsplit(
    const float* __restrict__ Wq, const float* __restrict__ Wk,
    const float* __restrict__ Wv,
    ushort* __restrict__ whT, ushort* __restrict__ wlT)
{
  const int idx  = blockIdx.x * 256 + threadIdx.x;  // 0..49151
  const int mat  = idx >> 14;                       // 16384 chunks per mat
  const int rem  = idx & 16383;
  const int nt   = rem >> 11;                       // 0..7
  const int kc   = (rem >> 6) & 31;                 // 0..31
  const int lane = rem & 63;
  const int quad = lane >> 4, l15 = lane & 15;
  const float* W = (mat == 0) ? Wq : (mat == 1) ? Wk : Wv;
  const int n  = nt * 16 + l15;
  const int k0 = kc * 32 + quad * 8;
  bf16x8 hv, lv;
  #pragma unroll
  for (int j = 0; j < 8; ++j) {
    const float f = W[(size_t)(k0 + j) * H_ + n];
    const ushort h = bf16_rne(f);
    hv[j] = (short)h;
    lv[j] = (short)bf16_rne(f - bf16_tof(h));
  }
  *(bf16x8*)(whT + (size_t)idx * 8) = hv;   // == FRAGW(mat*8+nt, kc, lane)
  *(bf16x8*)(wlT + (size_t)idx * 8) = lv;
}

// ---------------------------------------------------------------------------
// Kernel 1: fused QKV projection, round-10:
//  * m-tile 64 -> 32: grid (512, 2) = 1024 blocks = 4 blocks/CU (was 2).
//    Latency stalls (75% of step time at 2 blocks/CU) now overlap across
//    4 resident blocks. Per-wave: 2 m-tiles, 14 MFMA/step; LDS 8 KB.
//  * structure otherwise identical to round-9: A LDS double-buffered,
//    lgkmcnt-only barriers, 2 qk-tiles + 1 v-tile per wave.
// ---------------------------------------------------------------------------
#define PSTEP3(KC, CUR, NXT, BHC, BLC, BHN, BLN) do {                         \
    bf16x8 a_h_[2], a_l_[2];                                                  \
    _Pragma("unroll")                                                         \
    for (int mt_ = 0; mt_ < 2; ++mt_) {                                       \
      a_h_[mt_] = *(const bf16x8*)                                            \
          &SM[(CUR)*2048 + (((mt_*4 + quad)*16) + l15)*8];                    \
      a_l_[mt_] = *(const bf16x8*)                                            \
          &SM[(CUR)*2048 + 1024 + (((mt_*4 + quad)*16) + l15)*8];             \
    }                                                                         \
    float4 nf_;                                                               \
    if ((KC) + 2 < 32) {                                                      \
      nf_ = *(const float4*)(xrow + ((KC) + 2)*32);                           \
    } else { nf_ = xf; }                                                      \
    if ((KC) + 1 < 32) {                                                      \
      BHN[0] = *(const bf16x8*)(whT + FRAGW(gq,     (KC)+1, lane));           \
      BHN[1] = *(const bf16x8*)(whT + FRAGW(gq + 4, (KC)+1, lane));           \
      BHN[2] = *(const bf16x8*)(whT + FRAGW(gv,     (KC)+1, lane));           \
      BLN[0] = *(const bf16x8*)(wlT + FRAGW(gq,     (KC)+1, lane));           \
      BLN[1] = *(const bf16x8*)(wlT + FRAGW(gq + 4, (KC)+1, lane));           \
      const float f_[4] = {xf.x, xf.y, xf.z, xf.w};                           \
      bf16x4 hv_, lv_;                                                        \
      _Pragma("unroll")                                                       \
      for (int jj_ = 0; jj_ < 4; ++jj_) {                                     \
        const ushort h_ = bf16_rne(f_[jj_]);                                  \
        hv_[jj_] = (short)h_;                                                 \
        lv_[jj_] = (short)bf16_rne(f_[jj_] - bf16_tof(h_));                   \
      }                                                                       \
      *(bf16x4*)&SM[(NXT)*2048 + ca8] = hv_;                                  \
      *(bf16x4*)&SM[(NXT)*2048 + 1024 + ca8] = lv_;                           \
    }                                                                         \
    _Pragma("unroll")                                                         \
    for (int mt_ = 0; mt_ < 2; ++mt_) {                                       \
      acc[0][mt_] = mfma16(a_h_[mt_], BHC[0], acc[0][mt_]);                   \
      acc[0][mt_] = mfma16(a_h_[mt_], BLC[0], acc[0][mt_]);                   \
      acc[0][mt_] = mfma16(a_l_[mt_], BHC[0], acc[0][mt_]);                   \
      acc[1][mt_] = mfma16(a_h_[mt_], BHC[1], acc[1][mt_]);                   \
      acc[1][mt_] = mfma16(a_h_[mt_], BLC[1], acc[1][mt_]);                   \
      acc[1][mt_] = mfma16(a_l_[mt_], BHC[1], acc[1][mt_]);                   \
      acc[2][mt_] = mfma16(a_h_[mt_], BHC[2], acc[2][mt_]);                   \
    }                                                                         \
    xf = nf_;                                                                 \
    lds_barrier();                                                            \
  } while (0)

__global__ __launch_bounds__(256) void proj_fused(
    const float* __restrict__ x,
    const ushort* __restrict__ whT, const ushort* __restrict__ wlT,
    ushort* __restrict__ qh, ushort* __restrict__ ql,
    ushort* __restrict__ kfh, ushort* __restrict__ kfl,
    ushort* __restrict__ vF)
{
  const int m0   = blockIdx.x * 32;
  const int half = blockIdx.y;
  const int tid  = threadIdx.x;
  const int wave = tid >> 6, lane = tid & 63;
  const int quad = lane >> 4, l15 = lane & 15;

  __shared__ __align__(16) ushort SM[4096];  // A dbuf [2][Ah 1024|Al 1024] / smT

  f32x4 acc[3][2];
  #pragma unroll
  for (int j = 0; j < 3; ++j)
    #pragma unroll
    for (int mt = 0; mt < 2; ++mt) acc[j][mt] = (f32x4){0.f, 0.f, 0.f, 0.f};

  const int arow  = tid >> 3;          // 0..31
  const int akoff = (tid & 7) * 4;     // 0,4,...,28
  // A-frag chunk: ((row>>4)*4 + (k>>3))*16 + (row&15), elem k&7
  const int ca8   = ((((arow >> 4) * 4 + (akoff >> 3)) * 16 + (arow & 15))) * 8
                    + (akoff & 7);
  const int gq    = half * 8 + wave;   // qk tiles: gq (j=0), gq+4 (j=1)
  const int gv    = 16 + half * 4 + wave;  // v tile (j=2)

  const float* xrow = x + (size_t)(m0 + arow) * E_ + akoff;

  float4 xf;                       // x floats for step kc+1
  bf16x8 bhA[3], blA[2], bhB[3], blB[2];

  // ---- prologue: A(0) -> buf0; prefetch xf(1), B(0) ----
  {
    const float4 f0 = *(const float4*)xrow;
    const float f_[4] = {f0.x, f0.y, f0.z, f0.w};
    bf16x4 hv, lv;
    #pragma unroll
    for (int jj = 0; jj < 4; ++jj) {
      const ushort h = bf16_rne(f_[jj]);
      hv[jj] = (short)h;
      lv[jj] = (short)bf16_rne(f_[jj] - bf16_tof(h));
    }
    *(bf16x4*)&SM[ca8] = hv;
    *(bf16x4*)&SM[1024 + ca8] = lv;
    xf = *(const float4*)(xrow + 32);
    bhA[0] = *(const bf16x8*)(whT + FRAGW(gq,     0, lane));
    bhA[1] = *(const bf16x8*)(whT + FRAGW(gq + 4, 0, lane));
    bhA[2] = *(const bf16x8*)(whT + FRAGW(gv,     0, lane));
    blA[0] = *(const bf16x8*)(wlT + FRAGW(gq,     0, lane));
    blA[1] = *(const bf16x8*)(wlT + FRAGW(gq + 4, 0, lane));
  }
  lds_barrier();

  int kc = 0;
  while (true) {
    PSTEP3(kc, 0, 1, bhA, blA, bhB, blB); if (++kc == 32) break;
    PSTEP3(kc, 1, 0, bhB, blB, bhA, blA); if (++kc == 32) break;
  }

  // ---- epilogue: j<2 -> q (half0) in [t][h] / k (half1) in frag order ----
  #pragma unroll
  for (int j = 0; j < 2; ++j) {
    const int g = gq + 4 * j;
    if (half == 0) {                           // q: g in 0..7
      const int ncol = g * 16 + l15;
      #pragma unroll
      for (int mt = 0; mt < 2; ++mt)
        #pragma unroll
        for (int r = 0; r < 4; ++r) {
          const float a = acc[j][mt][r];
          const ushort h = bf16_rne(a);
          const size_t off = (size_t)(m0 + mt * 16 + quad * 4 + r) * H_ + ncol;
          qh[off] = h;
          ql[off] = bf16_rne(a - bf16_tof(h));
        }
    } else {                                   // k: g in 8..15 -> frag order
      const int hcol = (g - 8) * 16 + l15;
      const int kch  = hcol >> 5;
      const int qdh  = (hcol >> 3) & 3;
      const int jj   = hcol & 7;
      #pragma unroll
      for (int mt = 0; mt < 2; ++mt)
        #pragma unroll
        for (int r = 0; r < 4; ++r) {
          const float a = acc[j][mt][r];
          const int tg = m0 + mt * 16 + quad * 4 + r;
          const int bb = tg >> 11, tl = tg & 2047;
          const size_t ad = FRAGK(bb, tl >> 4, kch, qdh * 16 + (tl & 15)) + jj;
          const ushort h = bf16_rne(a);
          kfh[ad] = h;
          kfl[ad] = bf16_rne(a - bf16_tof(h));
        }
    }
  }
  // ---- epilogue: v (both halves, 64 h-cols each) via LDS transpose ----
  {
    ushort* smT = SM;                          // [64 hcols][40] (pad: 16B align)
    const int lh = wave * 16 + l15;            // 0..63 (local h col)
    #pragma unroll
    for (int mt = 0; mt < 2; ++mt)
      #pragma unroll
      for (int r = 0; r < 4; ++r)
        smT[lh * 40 + mt * 16 + quad * 4 + r] = bf16_rne(acc[2][mt][r]);
    __syncthreads();
    const int bb = m0 >> 11, t0 = m0 & 2047;
    {
      const int c    = tid;                    // 256 = 4 lht x 64 lane
      const int lht  = c >> 6;                 // 0..3
      const int lv   = c & 63;
      const int qv   = lv >> 4, l15v = lv & 15;
      *(bf16x8*)(vF + FRAGV(bb, half * 4 + lht, t0 >> 5, lv)) =
          *(const bf16x8*)&smT[(lht * 16 + l15v) * 40 + qv * 8];
    }
  }
}

// ---------------------------------------------------------------------------
// Kernel 2: block flash attention, split-K (unchanged this round).
// ---------------------------------------------------------------------------
__global__ __launch_bounds__(256) void attn_flash(
    const ushort* __restrict__ qh, const ushort* __restrict__ ql,
    const ushort* __restrict__ kfh, const ushort* __restrict__ kfl,
    const ushort* __restrict__ vF,
    ushort* __restrict__ Opart, float* __restrict__ mlpart)
{
  const int b    = (int)blockIdx.x & 7;        // %8 -> XCD pin
  const int seg  = (int)blockIdx.x >> 3;
  const int qt   = 31 - (int)blockIdx.y;       // heavy first
  const int q0   = qt * 64;
  const int tid  = threadIdx.x;
  const int wave = tid >> 6, lane = tid & 63;
  const int quad = lane >> 4, l15 = lane & 15;
  const f32x4 z4 = (f32x4){0.f, 0.f, 0.f, 0.f};

  __shared__ __align__(16) ushort KhS[4096];   // [s(2)][kc(4)][lane][8] linear
  __shared__ __align__(16) ushort KlS[4096];
  __shared__ __align__(16) ushort VtS[4096];   // [ht(8)][lane][8] linear
  __shared__ __align__(16) ushort smP[4 * 640];

  const int ntiles = 2 * qt + 2;
  const int cnt    = (ntiles + SEG_ - 1) >> 2;
  const int jt0    = seg * cnt;
  const int jt1    = (jt0 + cnt < ntiles) ? (jt0 + cnt) : ntiles;

  const int q0w = q0 + wave * 16;
  const int ntw = ((q0w + 15) >> 5) + 1;
  const size_t pidx = ((size_t)(b * 128 + qt * 4 + wave)) * SEG_ + seg;
  ushort* op = Opart + pidx * 2048;
  float*  ml = mlpart + pidx * 32;

  if (jt0 >= jt1) {
    const bf16x8 zz = {0, 0, 0, 0, 0, 0, 0, 0};
    #pragma unroll
    for (int u = 0; u < 4; ++u)
      *(bf16x8*)(op + lane * 32 + u * 8) = zz;
    if (lane < 32) ml[lane] = (lane & 1) ? 0.f : -1e30f;
    return;
  }

  const size_t base = (size_t)b * T_ * H_;

  const ushort* qhp = qh + base + (size_t)(q0w + l15) * H_ + quad * 8;
  const ushort* qlp = ql + base + (size_t)(q0w + l15) * H_ + quad * 8;
  bf16x8 Qh[4], Ql[4];
  #pragma unroll
  for (int c = 0; c < 4; ++c) {
    Qh[c] = *(const bf16x8*)(qhp + c * 32);
    Ql[c] = *(const bf16x8*)(qlp + c * 32);
  }

  f32x4 O[8];
  #pragma unroll
  for (int i = 0; i < 8; ++i) O[i] = z4;
  float mstate[4] = {-1e30f, -1e30f, -1e30f, -1e30f};
  float lstate[4] = {0.f, 0.f, 0.f, 0.f};

  bf16x8 rkh[2], rkl[2], rv[2];
  {
    #pragma unroll
    for (int u = 0; u < 2; ++u) {
      const int c = u * 256 + tid;
      rkh[u] = *(const bf16x8*)(kfh + FRAGK(b, 2 * jt0 + (c >> 8), (c >> 6) & 3, c & 63));
      rkl[u] = *(const bf16x8*)(kfl + FRAGK(b, 2 * jt0 + (c >> 8), (c >> 6) & 3, c & 63));
      rv[u]  = *(const bf16x8*)(vF  + FRAGV(b, c >> 6, jt0, c & 63));
    }
  }

  for (int jt = jt0; jt < jt1; ++jt) {
    __syncthreads();
    #pragma unroll
    for (int u = 0; u < 2; ++u) {
      const int c = u * 256 + tid;
      *(bf16x8*)&KhS[c * 8] = rkh[u];
      *(bf16x8*)&KlS[c * 8] = rkl[u];
      *(bf16x8*)&VtS[c * 8] = rv[u];
    }
    __syncthreads();

    if (jt + 1 < jt1) {
      #pragma unroll
      for (int u = 0; u < 2; ++u) {
        const int c = u * 256 + tid;
        rkh[u] = *(const bf16x8*)(kfh + FRAGK(b, 2 * (jt + 1) + (c >> 8), (c >> 6) & 3, c & 63));
        rkl[u] = *(const bf16x8*)(kfl + FRAGK(b, 2 * (jt + 1) + (c >> 8), (c >> 6) & 3, c & 63));
        rv[u]  = *(const bf16x8*)(vF  + FRAGV(b, c >> 6, jt + 1, c & 63));
      }
    }

    if (jt < ntw) {
      const int k0 = jt * 32;
      f32x4 shh0 = z4, shh1 = z4, sx0 = z4, sx1 = z4;
      #pragma unroll
      for (int c = 0; c < 4; ++c) {
        const bf16x8 kh0 = *(const bf16x8*)&KhS[(c * 64 + lane) * 8];
        const bf16x8 kh1 = *(const bf16x8*)&KhS[((4 + c) * 64 + lane) * 8];
        const bf16x8 kl0 = *(const bf16x8*)&KlS[(c * 64 + lane) * 8];
        const bf16x8 kl1 = *(const bf16x8*)&KlS[((4 + c) * 64 + lane) * 8];
        shh0 = mfma16(Qh[c], kh0, shh0);
        shh1 = mfma16(Qh[c], kh1, shh1);
        sx0  = mfma16(Qh[c], kl0, sx0);
        sx1  = mfma16(Qh[c], kl1, sx1);
        sx0  = mfma16(Ql[c], kh0, sx0);
        sx1  = mfma16(Ql[c], kh1, sx1);
      }

      float s0[4], s1[4];
      #pragma unroll
      for (int r = 0; r < 4; ++r) {
        s0[r] = (shh0[r] + sx0[r]) * SCALE_;
        s1[r] = (shh1[r] + sx1[r]) * SCALE_;
      }
      if (jt == ntw - 1) {
        const int krel0 = k0 + l15      - q0w - quad * 4;
        const int krel1 = k0 + 16 + l15 - q0w - quad * 4;
        #pragma unroll
        for (int r = 0; r < 4; ++r) {
          if (krel0 > r) s0[r] = -1e30f;
          if (krel1 > r) s1[r] = -1e30f;
        }
      }

      float alpha[4];
      #pragma unroll
      for (int r = 0; r < 4; ++r) {
        const float rm   = rowmax16(fmaxf(s0[r], s1[r]));
        const float mnew = fmaxf(mstate[r], rm);
        alpha[r] = __expf(mstate[r] - mnew);
        mstate[r] = mnew;
        const float p0 = __expf(s0[r] - mnew);
        const float p1 = __expf(s1[r] - mnew);
        lstate[r] = lstate[r] * alpha[r] + rowsum16(p0 + p1);
        smP[wave * 640 + (quad * 4 + r) * 40 + l15]      = bf16_rne(p0);
        smP[wave * 640 + (quad * 4 + r) * 40 + 16 + l15] = bf16_rne(p1);
      }
      #pragma unroll
      for (int ct = 0; ct < 8; ++ct) {
        O[ct][0] *= alpha[0]; O[ct][1] *= alpha[1];
        O[ct][2] *= alpha[2]; O[ct][3] *= alpha[3];
      }
      const bf16x8 pA = *(const bf16x8*)&smP[wave * 640 + l15 * 40 + quad * 8];
      #pragma unroll
      for (int ct = 0; ct < 8; ++ct) {
        const bf16x8 vf = *(const bf16x8*)&VtS[(ct * 64 + lane) * 8];
        O[ct] = mfma16(pA, vf, O[ct]);
      }
    }
  }

  #pragma unroll
  for (int r = 0; r < 4; ++r)
    #pragma unroll
    for (int ct = 0; ct < 8; ++ct)
      op[(quad * 4 + r) * 128 + ct * 16 + l15] = bf16_rne(O[ct][r]);
  if (l15 == 0) {
    #pragma unroll
    for (int r = 0; r < 4; ++r) {
      ml[(quad * 4 + r) * 2]     = mstate[r];
      ml[(quad * 4 + r) * 2 + 1] = lstate[r];
    }
  }
}

// ---------------------------------------------------------------------------
// Kernel 3: combine 4 split-K partials per q-row (unchanged).
// ---------------------------------------------------------------------------
__global__ __launch_bounds__(256) void attn_combine(
    const ushort* __restrict__ Opart, const float* __restrict__ mlpart,
    float* __restrict__ out)
{
  const int idx = blockIdx.x * 256 + threadIdx.x;
  const int c4  = idx & 31;
  const int r   = idx >> 5;
  const int t   = r & 2047;
  const int qt  = t >> 4, r16 = t & 15;
  const size_t pb = ((size_t)((r >> 11) * 128 + qt)) * SEG_;

  float m[SEG_], l[SEG_];
  #pragma unroll
  for (int s = 0; s < SEG_; ++s) {
    m[s] = mlpart[(pb + s) * 32 + r16 * 2];
    l[s] = mlpart[(pb + s) * 32 + r16 * 2 + 1];
  }
  float M = m[0];
  #pragma unroll
  for (int s = 1; s < SEG_; ++s) M = fmaxf(M, m[s]);
  float w[SEG_], L = 0.f;
  #pragma unroll
  for (int s = 0; s < SEG_; ++s) {
    w[s] = __expf(m[s] - M);
    L += l[s] * w[s];
  }
  float4 acc = make_float4(0.f, 0.f, 0.f, 0.f);
  #pragma unroll
  for (int s = 0; s < SEG_; ++s) {
    const ushort4 o = *(const ushort4*)(Opart + (pb + s) * 2048 + r16 * 128 + c4 * 4);
    acc.x += w[s] * bf16_tof(o.x);
    acc.y += w[s] * bf16_tof(o.y);
    acc.z += w[s] * bf16_tof(o.z);
    acc.w += w[s] * bf16_tof(o.w);
  }
  const float inv = 1.0f / L;
  *(float4*)(out + (size_t)r * H_ + c4 * 4) =
      make_float4(acc.x * inv, acc.y * inv, acc.z * inv, acc.w * inv);
}

// ---------------------------------------------------------------------------
extern "C" void kernel_launch(void* const* d_in, const int* in_sizes, int n_in,
                              void* d_out, int out_size, void* d_ws, size_t ws_size,
                              hipStream_t stream) {
  (void)in_sizes; (void)n_in; (void)out_size; (void)ws_size;
  const float* x  = (const float*)d_in[0];
  const float* Wq = (const float*)d_in[1];
  const float* Wk = (const float*)d_in[2];
  const float* Wv = (const float*)d_in[3];
  float* out = (float*)d_out;

  ushort* qhb = (ushort*)d_ws;
  ushort* qlb = qhb + (size_t)M_ * H_;
  ushort* kfh = qlb + (size_t)M_ * H_;
  ushort* kfl = kfh + (size_t)M_ * H_;
  ushort* vFb = kfl + (size_t)M_ * H_;
  ushort* whT = vFb + (size_t)M_ * H_;
  ushort* wlT = whT + (size_t)3 * H_ * E_;
  ushort* Opart = wlT + (size_t)3 * H_ * E_;
  float*  mlpart = (float*)(Opart + (size_t)B_ * 128 * SEG_ * 2048);

  wsplit<<<dim3(192), 256, 0, stream>>>(Wq, Wk, Wv, whT, wlT);
  proj_fused<<<dim3(M_/32, 2), 256, 0, stream>>>(x, whT, wlT,
                                                 qhb, qlb, kfh, kfl, vFb);
  attn_flash<<<dim3(B_*SEG_, 32), 256, 0, stream>>>(qhb, qlb, kfh, kfl, vFb,
                                                    Opart, mlpart);
  attn_combine<<<dim3(2048), 256, 0, stream>>>(Opart, mlpart, out);
}

// Round 4
// 174.311 us; speedup vs baseline: 1.0892x; 1.0892x over previous
//
#include <hip/hip_runtime.h>
#include <hip/hip_bf16.h>
#include <math.h>

#define B_ 8
#define T_ 2048
#define E_ 1024
#define H_ 128
#define M_ (B_*T_)              // 16384
#define SCALE_ 45.25483399593904f   // sqrt(2048) per reference
#define SEG_ 4                      // key-range split factor for attention

typedef __attribute__((ext_vector_type(8))) short bf16x8;
typedef __attribute__((ext_vector_type(4))) float f32x4;

#define mfma16(A, Bv, C) __builtin_amdgcn_mfma_f32_16x16x32_bf16((A), (Bv), (C), 0, 0, 0)

// ---- fragment-order flat indices (ushort elements) -------------------------
// lane = quad*16 + l15 throughout.
// W-frag (proj B operand): g = mat*8+nt (0..23), kc = k/32 (0..31);
//   element (n = (g&7)*16 + l15, k = kc*32 + quad*8 + j)
#define FRAGW(g, kc, lane)  ((((size_t)(g)*32 + (kc))*64 + (lane))*8)
// K-frag (attn QK B operand): kt16 = key/16 (0..127), kc = h/32 (0..3);
//   element (key = kt16*16 + l15, h = kc*32 + quad*8 + j)
#define FRAGK(b, kt16, kc, lane) (((((size_t)(b)*128 + (kt16))*4 + (kc))*64 + (lane))*8)
// V-frag (attn PV B operand): ht = h/16 (0..7), kt32 = key/32 (0..63);
//   element (h = ht*16 + l15, key = kt32*32 + quad*8 + j)
#define FRAGV(b, ht, kt32, lane) (((((size_t)(b)*8 + (ht))*64 + (kt32))*64 + (lane))*8)

__device__ __forceinline__ ushort bf16_rne(float f) {
  unsigned u = __float_as_uint(f);
  u += 0x7fffu + ((u >> 16) & 1u);
  return (ushort)(u >> 16);
}
__device__ __forceinline__ float bf16_tof(ushort h) {
  return __uint_as_float(((unsigned)h) << 16);
}

// LDS-only barrier: drain DS ops (cross-wave LDS dependency) but leave
// register-destined global prefetches (vmcnt) in flight across the barrier.
__device__ __forceinline__ void lds_barrier() {
  asm volatile("s_waitcnt lgkmcnt(0)" ::: "memory");
  __builtin_amdgcn_s_barrier();
}

// DPP row_ror:N within 16-lane rows; rotate-reduce leaves result in all lanes.
template <int N>
__device__ __forceinline__ float ror16(float x) {
  return __uint_as_float((unsigned)__builtin_amdgcn_update_dpp(
      0, (int)__float_as_uint(x), 0x120 + N, 0xF, 0xF, true));
}
__device__ __forceinline__ float rowmax16(float x) {
  x = fmaxf(x, ror16<8>(x));
  x = fmaxf(x, ror16<4>(x));
  x = fmaxf(x, ror16<2>(x));
  x = fmaxf(x, ror16<1>(x));
  return x;
}
__device__ __forceinline__ float rowsum16(float x) {
  x += ror16<8>(x);
  x += ror16<4>(x);
  x += ror16<2>(x);
  x += ror16<1>(x);
  return x;
}

// ---------------------------------------------------------------------------
// Kernel 0: split W -> whT/wlT bf16 in PROJ-B FRAGMENT ORDER. (unchanged)
// ---------------------------------------------------------------------------
__global__ __launch_bounds__(256) void wsplit(
    const float* __restrict__ Wq, const float* __restrict__ Wk,
    const float* __restrict__ Wv,
    ushort* __restrict__ whT, ushort* __restrict__ wlT)
{
  const int idx  = blockIdx.x * 256 + threadIdx.x;  // 0..49151
  const int mat  = idx >> 14;                       // 16384 chunks per mat
  const int rem  = idx & 16383;
  const int nt   = rem >> 11;                       // 0..7
  const int kc   = (rem >> 6) & 31;                 // 0..31
  const int lane = rem & 63;
  const int quad = lane >> 4, l15 = lane & 15;
  const float* W = (mat == 0) ? Wq : (mat == 1) ? Wk : Wv;
  const int n  = nt * 16 + l15;
  const int k0 = kc * 32 + quad * 8;
  bf16x8 hv, lv;
  #pragma unroll
  for (int j = 0; j < 8; ++j) {
    const float f = W[(size_t)(k0 + j) * H_ + n];
    const ushort h = bf16_rne(f);
    hv[j] = (short)h;
    lv[j] = (short)bf16_rne(f - bf16_tof(h));
  }
  *(bf16x8*)(whT + (size_t)idx * 8) = hv;   // == FRAGW(mat*8+nt, kc, lane)
  *(bf16x8*)(wlT + (size_t)idx * 8) = lv;
}

// ---------------------------------------------------------------------------
// Kernel 1: fused QKV projection, round-11 (r9 structure + BK=64):
//  * round-2/9 base (m-tile 64, grid (256,2), 2 blocks/CU) — r10's 4-block
//    split REGRESSED (fixed per-step overhead dominates; halving work/step
//    and doubling W traffic both hurt).
//  * BK 32 -> 64: TWO kc-columns per loop step under ONE barrier.
//    16 barriers (was 32); 56 MFMA/wave/step (was 28) amortizes the
//    fixed per-step cost (B-issue + LDS round-trip + barrier ~2900 cy).
//  * A LDS: 2 buffers x 16 KB ([Ah0|Al0|Ah1|Al1] x 2048 ushorts).
//  * accumulation order over kc identical to r9 -> bitwise-same output.
// ---------------------------------------------------------------------------
#define CVT8W(F0, F1, DSTOFF) do {                                            \
    const float f_[8] = {(F0).x, (F0).y, (F0).z, (F0).w,                      \
                         (F1).x, (F1).y, (F1).z, (F1).w};                     \
    bf16x8 hv_, lv_;                                                          \
    _Pragma("unroll")                                                         \
    for (int jj_ = 0; jj_ < 8; ++jj_) {                                       \
      const ushort h_ = bf16_rne(f_[jj_]);                                    \
      hv_[jj_] = (short)h_;                                                   \
      lv_[jj_] = (short)bf16_rne(f_[jj_] - bf16_tof(h_));                     \
    }                                                                         \
    *(bf16x8*)&SM[(DSTOFF) + ca * 8] = hv_;                                   \
    *(bf16x8*)&SM[(DSTOFF) + 2048 + ca * 8] = lv_;                            \
  } while (0)

#define PSTEP4(S, CUR, NXT, BHC, BLC, BHN, BLN) do {                          \
    bf16x8 ah_[4], al_[4];                                                    \
    _Pragma("unroll")                                                         \
    for (int mt_ = 0; mt_ < 4; ++mt_) {                                       \
      ah_[mt_] = *(const bf16x8*)                                             \
          &SM[(CUR)*8192 + (((mt_*4 + quad)*16) + l15)*8];                    \
      al_[mt_] = *(const bf16x8*)                                             \
          &SM[(CUR)*8192 + 2048 + (((mt_*4 + quad)*16) + l15)*8];             \
    }                                                                         \
    if ((S) + 1 < 16) {                                                       \
      _Pragma("unroll")                                                       \
      for (int kch_ = 0; kch_ < 2; ++kch_) {                                  \
        const int kcn_ = 2*((S)+1) + kch_;                                    \
        BHN[kch_*3+0] = *(const bf16x8*)(whT + FRAGW(gq,     kcn_, lane));    \
        BHN[kch_*3+1] = *(const bf16x8*)(whT + FRAGW(gq + 4, kcn_, lane));    \
        BHN[kch_*3+2] = *(const bf16x8*)(whT + FRAGW(gv,     kcn_, lane));    \
        BLN[kch_*2+0] = *(const bf16x8*)(wlT + FRAGW(gq,     kcn_, lane));    \
        BLN[kch_*2+1] = *(const bf16x8*)(wlT + FRAGW(gq + 4, kcn_, lane));    \
      }                                                                       \
    }                                                                         \
    float4 nx0_, nx1_, nx2_, nx3_;                                            \
    if ((S) + 2 < 16) {                                                       \
      nx0_ = *(const float4*)(xrow + 64*((S)+2));                             \
      nx1_ = *(const float4*)(xrow + 64*((S)+2) + 4);                         \
      nx2_ = *(const float4*)(xrow + 64*((S)+2) + 32);                        \
      nx3_ = *(const float4*)(xrow + 64*((S)+2) + 36);                        \
    } else { nx0_ = xf0; nx1_ = xf1; nx2_ = xf2; nx3_ = xf3; }                \
    /* MFMA kch0 (kc = 2S) */                                                 \
    _Pragma("unroll")                                                         \
    for (int mt_ = 0; mt_ < 4; ++mt_) {                                       \
      acc[0][mt_] = mfma16(ah_[mt_], BHC[0], acc[0][mt_]);                    \
      acc[0][mt_] = mfma16(ah_[mt_], BLC[0], acc[0][mt_]);                    \
      acc[0][mt_] = mfma16(al_[mt_], BHC[0], acc[0][mt_]);                    \
      acc[1][mt_] = mfma16(ah_[mt_], BHC[1], acc[1][mt_]);                    \
      acc[1][mt_] = mfma16(ah_[mt_], BLC[1], acc[1][mt_]);                    \
      acc[1][mt_] = mfma16(al_[mt_], BHC[1], acc[1][mt_]);                    \
      acc[2][mt_] = mfma16(ah_[mt_], BHC[2], acc[2][mt_]);                    \
    }                                                                         \
    /* stage A(S+1) into NXT buffer */                                        \
    if ((S) + 1 < 16) {                                                       \
      CVT8W(xf0, xf1, (NXT)*8192);                                            \
      CVT8W(xf2, xf3, (NXT)*8192 + 4096);                                     \
    }                                                                         \
    /* A-frags kch1 (kc = 2S+1) */                                            \
    _Pragma("unroll")                                                         \
    for (int mt_ = 0; mt_ < 4; ++mt_) {                                       \
      ah_[mt_] = *(const bf16x8*)                                             \
          &SM[(CUR)*8192 + 4096 + (((mt_*4 + quad)*16) + l15)*8];             \
      al_[mt_] = *(const bf16x8*)                                             \
          &SM[(CUR)*8192 + 6144 + (((mt_*4 + quad)*16) + l15)*8];             \
    }                                                                         \
    _Pragma("unroll")                                                         \
    for (int mt_ = 0; mt_ < 4; ++mt_) {                                       \
      acc[0][mt_] = mfma16(ah_[mt_], BHC[3], acc[0][mt_]);                    \
      acc[0][mt_] = mfma16(ah_[mt_], BLC[2], acc[0][mt_]);                    \
      acc[0][mt_] = mfma16(al_[mt_], BHC[3], acc[0][mt_]);                    \
      acc[1][mt_] = mfma16(ah_[mt_], BHC[4], acc[1][mt_]);                    \
      acc[1][mt_] = mfma16(ah_[mt_], BLC[3], acc[1][mt_]);                    \
      acc[1][mt_] = mfma16(al_[mt_], BHC[4], acc[1][mt_]);                    \
      acc[2][mt_] = mfma16(ah_[mt_], BHC[5], acc[2][mt_]);                    \
    }                                                                         \
    xf0 = nx0_; xf1 = nx1_; xf2 = nx2_; xf3 = nx3_;                           \
    lds_barrier();                                                            \
  } while (0)

__global__ __launch_bounds__(256, 2) void proj_fused(
    const float* __restrict__ x,
    const ushort* __restrict__ whT, const ushort* __restrict__ wlT,
    ushort* __restrict__ qh, ushort* __restrict__ ql,
    ushort* __restrict__ kfh, ushort* __restrict__ kfl,
    ushort* __restrict__ vF)
{
  const int m0   = blockIdx.x * 64;
  const int half = blockIdx.y;
  const int tid  = threadIdx.x;
  const int wave = tid >> 6, lane = tid & 63;
  const int quad = lane >> 4, l15 = lane & 15;

  __shared__ __align__(16) ushort SM[16384]; // 32KB: 2 bufs x [Ah0|Al0|Ah1|Al1]

  f32x4 acc[3][4];
  #pragma unroll
  for (int j = 0; j < 3; ++j)
    #pragma unroll
    for (int mt = 0; mt < 4; ++mt) acc[j][mt] = (f32x4){0.f, 0.f, 0.f, 0.f};

  const int arow  = tid >> 2;          // 0..63
  const int akoff = (tid & 3) * 8;     // 0,8,16,24
  const int ca    = ((arow >> 4) * 4 + (tid & 3)) * 16 + (arow & 15);
  const int gq    = half * 8 + wave;   // qk tiles: gq (j=0), gq+4 (j=1)
  const int gv    = 16 + half * 4 + wave;  // v tile (j=2)

  const float* xrow = x + (size_t)(m0 + arow) * E_ + akoff;

  float4 xf0, xf1, xf2, xf3;       // x floats for step S+1 (kc 2S+2, 2S+3)
  bf16x8 bhA[6], blA[4], bhB[6], blB[4];

  // ---- prologue: A(step0: kc0,kc1) -> buf0; prefetch xf(step1), B(step0) --
  {
    const float4 a0 = *(const float4*)(xrow);
    const float4 a1 = *(const float4*)(xrow + 4);
    const float4 a2 = *(const float4*)(xrow + 32);
    const float4 a3 = *(const float4*)(xrow + 36);
    CVT8W(a0, a1, 0);
    CVT8W(a2, a3, 4096);
    xf0 = *(const float4*)(xrow + 64);
    xf1 = *(const float4*)(xrow + 68);
    xf2 = *(const float4*)(xrow + 96);
    xf3 = *(const float4*)(xrow + 100);
    #pragma unroll
    for (int kch = 0; kch < 2; ++kch) {
      bhA[kch*3+0] = *(const bf16x8*)(whT + FRAGW(gq,     kch, lane));
      bhA[kch*3+1] = *(const bf16x8*)(whT + FRAGW(gq + 4, kch, lane));
      bhA[kch*3+2] = *(const bf16x8*)(whT + FRAGW(gv,     kch, lane));
      blA[kch*2+0] = *(const bf16x8*)(wlT + FRAGW(gq,     kch, lane));
      blA[kch*2+1] = *(const bf16x8*)(wlT + FRAGW(gq + 4, kch, lane));
    }
  }
  lds_barrier();

  int s = 0;
  while (true) {
    PSTEP4(s, 0, 1, bhA, blA, bhB, blB); if (++s == 16) break;
    PSTEP4(s, 1, 0, bhB, blB, bhA, blA); if (++s == 16) break;
  }

  // ---- epilogue: j<2 -> q (half0) in [t][h] / k (half1) in frag order ----
  #pragma unroll
  for (int j = 0; j < 2; ++j) {
    const int g = gq + 4 * j;
    if (half == 0) {                           // q: g in 0..7
      const int ncol = g * 16 + l15;
      #pragma unroll
      for (int mt = 0; mt < 4; ++mt)
        #pragma unroll
        for (int r = 0; r < 4; ++r) {
          const float a = acc[j][mt][r];
          const ushort h = bf16_rne(a);
          const size_t off = (size_t)(m0 + mt * 16 + quad * 4 + r) * H_ + ncol;
          qh[off] = h;
          ql[off] = bf16_rne(a - bf16_tof(h));
        }
    } else {                                   // k: g in 8..15 -> frag order
      const int hcol = (g - 8) * 16 + l15;
      const int kch  = hcol >> 5;
      const int qdh  = (hcol >> 3) & 3;
      const int jj   = hcol & 7;
      #pragma unroll
      for (int mt = 0; mt < 4; ++mt)
        #pragma unroll
        for (int r = 0; r < 4; ++r) {
          const float a = acc[j][mt][r];
          const int tg = m0 + mt * 16 + quad * 4 + r;
          const int bb = tg >> 11, tl = tg & 2047;
          const size_t ad = FRAGK(bb, tl >> 4, kch, qdh * 16 + (tl & 15)) + jj;
          const ushort h = bf16_rne(a);
          kfh[ad] = h;
          kfl[ad] = bf16_rne(a - bf16_tof(h));
        }
    }
  }
  // ---- epilogue: v (both halves, 64 h-cols each) via LDS transpose ----
  __syncthreads();
  {
    ushort* smT = SM;                          // [64][72] local-h x t
    const int lh = wave * 16 + l15;            // 0..63 (local h col)
    #pragma unroll
    for (int mt = 0; mt < 4; ++mt)
      #pragma unroll
      for (int r = 0; r < 4; ++r)
        smT[lh * 72 + mt * 16 + quad * 4 + r] = bf16_rne(acc[2][mt][r]);
    __syncthreads();
    const int bb = m0 >> 11, t0 = m0 & 2047;
    #pragma unroll
    for (int u = 0; u < 2; ++u) {
      const int c    = u * 256 + tid;          // 512 = 4 lht x 2 ktl x 64 lane
      const int lht  = c >> 7;                 // 0..3
      const int ktl  = (c >> 6) & 1;
      const int lv   = c & 63;
      const int qv   = lv >> 4, l15v = lv & 15;
      *(bf16x8*)(vF + FRAGV(bb, half * 4 + lht, (t0 >> 5) + ktl, lv)) =
          *(const bf16x8*)&smT[(lht * 16 + l15v) * 72 + ktl * 32 + qv * 8];
    }
  }
}

// ---------------------------------------------------------------------------
// Kernel 2: block flash attention, split-K (unchanged this round).
// ---------------------------------------------------------------------------
__global__ __launch_bounds__(256) void attn_flash(
    const ushort* __restrict__ qh, const ushort* __restrict__ ql,
    const ushort* __restrict__ kfh, const ushort* __restrict__ kfl,
    const ushort* __restrict__ vF,
    ushort* __restrict__ Opart, float* __restrict__ mlpart)
{
  const int b    = (int)blockIdx.x & 7;        // %8 -> XCD pin
  const int seg  = (int)blockIdx.x >> 3;
  const int qt   = 31 - (int)blockIdx.y;       // heavy first
  const int q0   = qt * 64;
  const int tid  = threadIdx.x;
  const int wave = tid >> 6, lane = tid & 63;
  const int quad = lane >> 4, l15 = lane & 15;
  const f32x4 z4 = (f32x4){0.f, 0.f, 0.f, 0.f};

  __shared__ __align__(16) ushort KhS[4096];   // [s(2)][kc(4)][lane][8] linear
  __shared__ __align__(16) ushort KlS[4096];
  __shared__ __align__(16) ushort VtS[4096];   // [ht(8)][lane][8] linear
  __shared__ __align__(16) ushort smP[4 * 640];

  const int ntiles = 2 * qt + 2;
  const int cnt    = (ntiles + SEG_ - 1) >> 2;
  const int jt0    = seg * cnt;
  const int jt1    = (jt0 + cnt < ntiles) ? (jt0 + cnt) : ntiles;

  const int q0w = q0 + wave * 16;
  const int ntw = ((q0w + 15) >> 5) + 1;
  const size_t pidx = ((size_t)(b * 128 + qt * 4 + wave)) * SEG_ + seg;
  ushort* op = Opart + pidx * 2048;
  float*  ml = mlpart + pidx * 32;

  if (jt0 >= jt1) {
    const bf16x8 zz = {0, 0, 0, 0, 0, 0, 0, 0};
    #pragma unroll
    for (int u = 0; u < 4; ++u)
      *(bf16x8*)(op + lane * 32 + u * 8) = zz;
    if (lane < 32) ml[lane] = (lane & 1) ? 0.f : -1e30f;
    return;
  }

  const size_t base = (size_t)b * T_ * H_;

  const ushort* qhp = qh + base + (size_t)(q0w + l15) * H_ + quad * 8;
  const ushort* qlp = ql + base + (size_t)(q0w + l15) * H_ + quad * 8;
  bf16x8 Qh[4], Ql[4];
  #pragma unroll
  for (int c = 0; c < 4; ++c) {
    Qh[c] = *(const bf16x8*)(qhp + c * 32);
    Ql[c] = *(const bf16x8*)(qlp + c * 32);
  }

  f32x4 O[8];
  #pragma unroll
  for (int i = 0; i < 8; ++i) O[i] = z4;
  float mstate[4] = {-1e30f, -1e30f, -1e30f, -1e30f};
  float lstate[4] = {0.f, 0.f, 0.f, 0.f};

  bf16x8 rkh[2], rkl[2], rv[2];
  {
    #pragma unroll
    for (int u = 0; u < 2; ++u) {
      const int c = u * 256 + tid;
      rkh[u] = *(const bf16x8*)(kfh + FRAGK(b, 2 * jt0 + (c >> 8), (c >> 6) & 3, c & 63));
      rkl[u] = *(const bf16x8*)(kfl + FRAGK(b, 2 * jt0 + (c >> 8), (c >> 6) & 3, c & 63));
      rv[u]  = *(const bf16x8*)(vF  + FRAGV(b, c >> 6, jt0, c & 63));
    }
  }

  for (int jt = jt0; jt < jt1; ++jt) {
    __syncthreads();
    #pragma unroll
    for (int u = 0; u < 2; ++u) {
      const int c = u * 256 + tid;
      *(bf16x8*)&KhS[c * 8] = rkh[u];
      *(bf16x8*)&KlS[c * 8] = rkl[u];
      *(bf16x8*)&VtS[c * 8] = rv[u];
    }
    __syncthreads();

    if (jt + 1 < jt1) {
      #pragma unroll
      for (int u = 0; u < 2; ++u) {
        const int c = u * 256 + tid;
        rkh[u] = *(const bf16x8*)(kfh + FRAGK(b, 2 * (jt + 1) + (c >> 8), (c >> 6) & 3, c & 63));
        rkl[u] = *(const bf16x8*)(kfl + FRAGK(b, 2 * (jt + 1) + (c >> 8), (c >> 6) & 3, c & 63));
        rv[u]  = *(const bf16x8*)(vF  + FRAGV(b, c >> 6, jt + 1, c & 63));
      }
    }

    if (jt < ntw) {
      const int k0 = jt * 32;
      f32x4 shh0 = z4, shh1 = z4, sx0 = z4, sx1 = z4;
      #pragma unroll
      for (int c = 0; c < 4; ++c) {
        const bf16x8 kh0 = *(const bf16x8*)&KhS[(c * 64 + lane) * 8];
        const bf16x8 kh1 = *(const bf16x8*)&KhS[((4 + c) * 64 + lane) * 8];
        const bf16x8 kl0 = *(const bf16x8*)&KlS[(c * 64 + lane) * 8];
        const bf16x8 kl1 = *(const bf16x8*)&KlS[((4 + c) * 64 + lane) * 8];
        shh0 = mfma16(Qh[c], kh0, shh0);
        shh1 = mfma16(Qh[c], kh1, shh1);
        sx0  = mfma16(Qh[c], kl0, sx0);
        sx1  = mfma16(Qh[c], kl1, sx1);
        sx0  = mfma16(Ql[c], kh0, sx0);
        sx1  = mfma16(Ql[c], kh1, sx1);
      }

      float s0[4], s1[4];
      #pragma unroll
      for (int r = 0; r < 4; ++r) {
        s0[r] = (shh0[r] + sx0[r]) * SCALE_;
        s1[r] = (shh1[r] + sx1[r]) * SCALE_;
      }
      if (jt == ntw - 1) {
        const int krel0 = k0 + l15      - q0w - quad * 4;
        const int krel1 = k0 + 16 + l15 - q0w - quad * 4;
        #pragma unroll
        for (int r = 0; r < 4; ++r) {
          if (krel0 > r) s0[r] = -1e30f;
          if (krel1 > r) s1[r] = -1e30f;
        }
      }

      float alpha[4];
      #pragma unroll
      for (int r = 0; r < 4; ++r) {
        const float rm   = rowmax16(fmaxf(s0[r], s1[r]));
        const float mnew = fmaxf(mstate[r], rm);
        alpha[r] = __expf(mstate[r] - mnew);
        mstate[r] = mnew;
        const float p0 = __expf(s0[r] - mnew);
        const float p1 = __expf(s1[r] - mnew);
        lstate[r] = lstate[r] * alpha[r] + rowsum16(p0 + p1);
        smP[wave * 640 + (quad * 4 + r) * 40 + l15]      = bf16_rne(p0);
        smP[wave * 640 + (quad * 4 + r) * 40 + 16 + l15] = bf16_rne(p1);
      }
      #pragma unroll
      for (int ct = 0; ct < 8; ++ct) {
        O[ct][0] *= alpha[0]; O[ct][1] *= alpha[1];
        O[ct][2] *= alpha[2]; O[ct][3] *= alpha[3];
      }
      const bf16x8 pA = *(const bf16x8*)&smP[wave * 640 + l15 * 40 + quad * 8];
      #pragma unroll
      for (int ct = 0; ct < 8; ++ct) {
        const bf16x8 vf = *(const bf16x8*)&VtS[(ct * 64 + lane) * 8];
        O[ct] = mfma16(pA, vf, O[ct]);
      }
    }
  }

  #pragma unroll
  for (int r = 0; r < 4; ++r)
    #pragma unroll
    for (int ct = 0; ct < 8; ++ct)
      op[(quad * 4 + r) * 128 + ct * 16 + l15] = bf16_rne(O[ct][r]);
  if (l15 == 0) {
    #pragma unroll
    for (int r = 0; r < 4; ++r) {
      ml[(quad * 4 + r) * 2]     = mstate[r];
      ml[(quad * 4 + r) * 2 + 1] = lstate[r];
    }
  }
}

// ---------------------------------------------------------------------------
// Kernel 3: combine 4 split-K partials per q-row (unchanged).
// ---------------------------------------------------------------------------
__global__ __launch_bounds__(256) void attn_combine(
    const ushort* __restrict__ Opart, const float* __restrict__ mlpart,
    float* __restrict__ out)
{
  const int idx = blockIdx.x * 256 + threadIdx.x;
  const int c4  = idx & 31;
  const int r   = idx >> 5;
  const int t   = r & 2047;
  const int qt  = t >> 4, r16 = t & 15;
  const size_t pb = ((size_t)((r >> 11) * 128 + qt)) * SEG_;

  float m[SEG_], l[SEG_];
  #pragma unroll
  for (int s = 0; s < SEG_; ++s) {
    m[s] = mlpart[(pb + s) * 32 + r16 * 2];
    l[s] = mlpart[(pb + s) * 32 + r16 * 2 + 1];
  }
  float M = m[0];
  #pragma unroll
  for (int s = 1; s < SEG_; ++s) M = fmaxf(M, m[s]);
  float w[SEG_], L = 0.f;
  #pragma unroll
  for (int s = 0; s < SEG_; ++s) {
    w[s] = __expf(m[s] - M);
    L += l[s] * w[s];
  }
  float4 acc = make_float4(0.f, 0.f, 0.f, 0.f);
  #pragma unroll
  for (int s = 0; s < SEG_; ++s) {
    const ushort4 o = *(const ushort4*)(Opart + (pb + s) * 2048 + r16 * 128 + c4 * 4);
    acc.x += w[s] * bf16_tof(o.x);
    acc.y += w[s] * bf16_tof(o.y);
    acc.z += w[s] * bf16_tof(o.z);
    acc.w += w[s] * bf16_tof(o.w);
  }
  const float inv = 1.0f / L;
  *(float4*)(out + (size_t)r * H_ + c4 * 4) =
      make_float4(acc.x * inv, acc.y * inv, acc.z * inv, acc.w * inv);
}

// ---------------------------------------------------------------------------
extern "C" void kernel_launch(void* const* d_in, const int* in_sizes, int n_in,
                              void* d_out, int out_size, void* d_ws, size_t ws_size,
                              hipStream_t stream) {
  (void)in_sizes; (void)n_in; (void)out_size; (void)ws_size;
  const float* x  = (const float*)d_in[0];
  const float* Wq = (const float*)d_in[1];
  const float* Wk = (const float*)d_in[2];
  const float* Wv = (const float*)d_in[3];
  float* out = (float*)d_out;

  ushort* qhb = (ushort*)d_ws;
  ushort* qlb = qhb + (size_t)M_ * H_;
  ushort* kfh = qlb + (size_t)M_ * H_;
  ushort* kfl = kfh + (size_t)M_ * H_;
  ushort* vFb = kfl + (size_t)M_ * H_;
  ushort* whT = vFb + (size_t)M_ * H_;
  ushort* wlT = whT + (size_t)3 * H_ * E_;
  ushort* Opart = wlT + (size_t)3 * H_ * E_;
  float*  mlpart = (float*)(Opart + (size_t)B_ * 128 * SEG_ * 2048);

  wsplit<<<dim3(192), 256, 0, stream>>>(Wq, Wk, Wv, whT, wlT);
  proj_fused<<<dim3(M_/64, 2), 256, 0, stream>>>(x, whT, wlT,
                                                 qhb, qlb, kfh, kfl, vFb);
  attn_flash<<<dim3(B_*SEG_, 32), 256, 0, stream>>>(qhb, qlb, kfh, kfl, vFb,
                                                    Opart, mlpart);
  attn_combine<<<dim3(2048), 256, 0, stream>>>(Opart, mlpart, out);
}

// Round 5
// 170.389 us; speedup vs baseline: 1.1143x; 1.0230x over previous
//
#include <hip/hip_runtime.h>
#include <hip/hip_bf16.h>
#include <math.h>

#define B_ 8
#define T_ 2048
#define E_ 1024
#define H_ 128
#define M_ (B_*T_)              // 16384
#define SCALE_ 45.25483399593904f   // sqrt(2048) per reference
#define SEG_ 4                      // key-range split factor for attention

typedef __attribute__((ext_vector_type(8))) short bf16x8;
typedef __attribute__((ext_vector_type(4))) float f32x4;

#define mfma16(A, Bv, C) __builtin_amdgcn_mfma_f32_16x16x32_bf16((A), (Bv), (C), 0, 0, 0)

// ---- fragment-order flat indices (ushort elements) -------------------------
// lane = quad*16 + l15 throughout.
// W-frag (proj B operand): g = mat*8+nt (0..23), kc = k/32 (0..31);
//   element (n = (g&7)*16 + l15, k = kc*32 + quad*8 + j)
#define FRAGW(g, kc, lane)  ((((size_t)(g)*32 + (kc))*64 + (lane))*8)
// K-frag (attn QK A operand, swapped): kt16 = key/16 (0..127), kc = h/32 (0..3);
//   element (key = kt16*16 + l15, h = kc*32 + quad*8 + j)
#define FRAGK(b, kt16, kc, lane) (((((size_t)(b)*128 + (kt16))*4 + (kc))*64 + (lane))*8)
// V-frag (attn PV A operand, swapped): ht = h/16 (0..7), kt32 = key/32 (0..63);
//   element (h = ht*16 + l15, key = kt32*32 + quad*8 + j)
#define FRAGV(b, ht, kt32, lane) (((((size_t)(b)*8 + (ht))*64 + (kt32))*64 + (lane))*8)

__device__ __forceinline__ ushort bf16_rne(float f) {
  unsigned u = __float_as_uint(f);
  u += 0x7fffu + ((u >> 16) & 1u);
  return (ushort)(u >> 16);
}
__device__ __forceinline__ float bf16_tof(ushort h) {
  return __uint_as_float(((unsigned)h) << 16);
}

// LDS-only barrier: drain DS ops (cross-wave LDS dependency) but leave
// register-destined global prefetches (vmcnt) in flight across the barrier.
__device__ __forceinline__ void lds_barrier() {
  asm volatile("s_waitcnt lgkmcnt(0)" ::: "memory");
  __builtin_amdgcn_s_barrier();
}

// ---------------------------------------------------------------------------
// Kernel 0: split W -> whT/wlT bf16 in PROJ-B FRAGMENT ORDER. (unchanged)
// ---------------------------------------------------------------------------
__global__ __launch_bounds__(256) void wsplit(
    const float* __restrict__ Wq, const float* __restrict__ Wk,
    const float* __restrict__ Wv,
    ushort* __restrict__ whT, ushort* __restrict__ wlT)
{
  const int idx  = blockIdx.x * 256 + threadIdx.x;  // 0..49151
  const int mat  = idx >> 14;                       // 16384 chunks per mat
  const int rem  = idx & 16383;
  const int nt   = rem >> 11;                       // 0..7
  const int kc   = (rem >> 6) & 31;                 // 0..31
  const int lane = rem & 63;
  const int quad = lane >> 4, l15 = lane & 15;
  const float* W = (mat == 0) ? Wq : (mat == 1) ? Wk : Wv;
  const int n  = nt * 16 + l15;
  const int k0 = kc * 32 + quad * 8;
  bf16x8 hv, lv;
  #pragma unroll
  for (int j = 0; j < 8; ++j) {
    const float f = W[(size_t)(k0 + j) * H_ + n];
    const ushort h = bf16_rne(f);
    hv[j] = (short)h;
    lv[j] = (short)bf16_rne(f - bf16_tof(h));
  }
  *(bf16x8*)(whT + (size_t)idx * 8) = hv;   // == FRAGW(mat*8+nt, kc, lane)
  *(bf16x8*)(wlT + (size_t)idx * 8) = lv;
}

// ---------------------------------------------------------------------------
// Kernel 1: fused QKV projection (round-11 version, unchanged this round).
// ---------------------------------------------------------------------------
#define CVT8W(F0, F1, DSTOFF) do {                                            \
    const float f_[8] = {(F0).x, (F0).y, (F0).z, (F0).w,                      \
                         (F1).x, (F1).y, (F1).z, (F1).w};                     \
    bf16x8 hv_, lv_;                                                          \
    _Pragma("unroll")                                                         \
    for (int jj_ = 0; jj_ < 8; ++jj_) {                                       \
      const ushort h_ = bf16_rne(f_[jj_]);                                    \
      hv_[jj_] = (short)h_;                                                   \
      lv_[jj_] = (short)bf16_rne(f_[jj_] - bf16_tof(h_));                     \
    }                                                                         \
    *(bf16x8*)&SM[(DSTOFF) + ca * 8] = hv_;                                   \
    *(bf16x8*)&SM[(DSTOFF) + 2048 + ca * 8] = lv_;                            \
  } while (0)

#define PSTEP4(S, CUR, NXT, BHC, BLC, BHN, BLN) do {                          \
    bf16x8 ah_[4], al_[4];                                                    \
    _Pragma("unroll")                                                         \
    for (int mt_ = 0; mt_ < 4; ++mt_) {                                       \
      ah_[mt_] = *(const bf16x8*)                                             \
          &SM[(CUR)*8192 + (((mt_*4 + quad)*16) + l15)*8];                    \
      al_[mt_] = *(const bf16x8*)                                             \
          &SM[(CUR)*8192 + 2048 + (((mt_*4 + quad)*16) + l15)*8];             \
    }                                                                         \
    if ((S) + 1 < 16) {                                                       \
      _Pragma("unroll")                                                       \
      for (int kch_ = 0; kch_ < 2; ++kch_) {                                  \
        const int kcn_ = 2*((S)+1) + kch_;                                    \
        BHN[kch_*3+0] = *(const bf16x8*)(whT + FRAGW(gq,     kcn_, lane));    \
        BHN[kch_*3+1] = *(const bf16x8*)(whT + FRAGW(gq + 4, kcn_, lane));    \
        BHN[kch_*3+2] = *(const bf16x8*)(whT + FRAGW(gv,     kcn_, lane));    \
        BLN[kch_*2+0] = *(const bf16x8*)(wlT + FRAGW(gq,     kcn_, lane));    \
        BLN[kch_*2+1] = *(const bf16x8*)(wlT + FRAGW(gq + 4, kcn_, lane));    \
      }                                                                       \
    }                                                                         \
    float4 nx0_, nx1_, nx2_, nx3_;                                            \
    if ((S) + 2 < 16) {                                                       \
      nx0_ = *(const float4*)(xrow + 64*((S)+2));                             \
      nx1_ = *(const float4*)(xrow + 64*((S)+2) + 4);                         \
      nx2_ = *(const float4*)(xrow + 64*((S)+2) + 32);                        \
      nx3_ = *(const float4*)(xrow + 64*((S)+2) + 36);                        \
    } else { nx0_ = xf0; nx1_ = xf1; nx2_ = xf2; nx3_ = xf3; }                \
    /* MFMA kch0 (kc = 2S) */                                                 \
    _Pragma("unroll")                                                         \
    for (int mt_ = 0; mt_ < 4; ++mt_) {                                       \
      acc[0][mt_] = mfma16(ah_[mt_], BHC[0], acc[0][mt_]);                    \
      acc[0][mt_] = mfma16(ah_[mt_], BLC[0], acc[0][mt_]);                    \
      acc[0][mt_] = mfma16(al_[mt_], BHC[0], acc[0][mt_]);                    \
      acc[1][mt_] = mfma16(ah_[mt_], BHC[1], acc[1][mt_]);                    \
      acc[1][mt_] = mfma16(ah_[mt_], BLC[1], acc[1][mt_]);                    \
      acc[1][mt_] = mfma16(al_[mt_], BHC[1], acc[1][mt_]);                    \
      acc[2][mt_] = mfma16(ah_[mt_], BHC[2], acc[2][mt_]);                    \
    }                                                                         \
    /* stage A(S+1) into NXT buffer */                                        \
    if ((S) + 1 < 16) {                                                       \
      CVT8W(xf0, xf1, (NXT)*8192);                                            \
      CVT8W(xf2, xf3, (NXT)*8192 + 4096);                                     \
    }                                                                         \
    /* A-frags kch1 (kc = 2S+1) */                                            \
    _Pragma("unroll")                                                         \
    for (int mt_ = 0; mt_ < 4; ++mt_) {                                       \
      ah_[mt_] = *(const bf16x8*)                                             \
          &SM[(CUR)*8192 + 4096 + (((mt_*4 + quad)*16) + l15)*8];             \
      al_[mt_] = *(const bf16x8*)                                             \
          &SM[(CUR)*8192 + 6144 + (((mt_*4 + quad)*16) + l15)*8];             \
    }                                                                         \
    _Pragma("unroll")                                                         \
    for (int mt_ = 0; mt_ < 4; ++mt_) {                                       \
      acc[0][mt_] = mfma16(ah_[mt_], BHC[3], acc[0][mt_]);                    \
      acc[0][mt_] = mfma16(ah_[mt_], BLC[2], acc[0][mt_]);                    \
      acc[0][mt_] = mfma16(al_[mt_], BHC[3], acc[0][mt_]);                    \
      acc[1][mt_] = mfma16(ah_[mt_], BHC[4], acc[1][mt_]);                    \
      acc[1][mt_] = mfma16(ah_[mt_], BLC[3], acc[1][mt_]);                    \
      acc[1][mt_] = mfma16(al_[mt_], BHC[4], acc[1][mt_]);                    \
      acc[2][mt_] = mfma16(ah_[mt_], BHC[5], acc[2][mt_]);                    \
    }                                                                         \
    xf0 = nx0_; xf1 = nx1_; xf2 = nx2_; xf3 = nx3_;                           \
    lds_barrier();                                                            \
  } while (0)

__global__ __launch_bounds__(256, 2) void proj_fused(
    const float* __restrict__ x,
    const ushort* __restrict__ whT, const ushort* __restrict__ wlT,
    ushort* __restrict__ qh, ushort* __restrict__ ql,
    ushort* __restrict__ kfh, ushort* __restrict__ kfl,
    ushort* __restrict__ vF)
{
  const int m0   = blockIdx.x * 64;
  const int half = blockIdx.y;
  const int tid  = threadIdx.x;
  const int wave = tid >> 6, lane = tid & 63;
  const int quad = lane >> 4, l15 = lane & 15;

  __shared__ __align__(16) ushort SM[16384]; // 32KB: 2 bufs x [Ah0|Al0|Ah1|Al1]

  f32x4 acc[3][4];
  #pragma unroll
  for (int j = 0; j < 3; ++j)
    #pragma unroll
    for (int mt = 0; mt < 4; ++mt) acc[j][mt] = (f32x4){0.f, 0.f, 0.f, 0.f};

  const int arow  = tid >> 2;          // 0..63
  const int akoff = (tid & 3) * 8;     // 0,8,16,24
  const int ca    = ((arow >> 4) * 4 + (tid & 3)) * 16 + (arow & 15);
  const int gq    = half * 8 + wave;   // qk tiles: gq (j=0), gq+4 (j=1)
  const int gv    = 16 + half * 4 + wave;  // v tile (j=2)

  const float* xrow = x + (size_t)(m0 + arow) * E_ + akoff;

  float4 xf0, xf1, xf2, xf3;       // x floats for step S+1 (kc 2S+2, 2S+3)
  bf16x8 bhA[6], blA[4], bhB[6], blB[4];

  // ---- prologue: A(step0: kc0,kc1) -> buf0; prefetch xf(step1), B(step0) --
  {
    const float4 a0 = *(const float4*)(xrow);
    const float4 a1 = *(const float4*)(xrow + 4);
    const float4 a2 = *(const float4*)(xrow + 32);
    const float4 a3 = *(const float4*)(xrow + 36);
    CVT8W(a0, a1, 0);
    CVT8W(a2, a3, 4096);
    xf0 = *(const float4*)(xrow + 64);
    xf1 = *(const float4*)(xrow + 68);
    xf2 = *(const float4*)(xrow + 96);
    xf3 = *(const float4*)(xrow + 100);
    #pragma unroll
    for (int kch = 0; kch < 2; ++kch) {
      bhA[kch*3+0] = *(const bf16x8*)(whT + FRAGW(gq,     kch, lane));
      bhA[kch*3+1] = *(const bf16x8*)(whT + FRAGW(gq + 4, kch, lane));
      bhA[kch*3+2] = *(const bf16x8*)(whT + FRAGW(gv,     kch, lane));
      blA[kch*2+0] = *(const bf16x8*)(wlT + FRAGW(gq,     kch, lane));
      blA[kch*2+1] = *(const bf16x8*)(wlT + FRAGW(gq + 4, kch, lane));
    }
  }
  lds_barrier();

  int s = 0;
  while (true) {
    PSTEP4(s, 0, 1, bhA, blA, bhB, blB); if (++s == 16) break;
    PSTEP4(s, 1, 0, bhB, blB, bhA, blA); if (++s == 16) break;
  }

  // ---- epilogue: j<2 -> q (half0) in [t][h] / k (half1) in frag order ----
  #pragma unroll
  for (int j = 0; j < 2; ++j) {
    const int g = gq + 4 * j;
    if (half == 0) {                           // q: g in 0..7
      const int ncol = g * 16 + l15;
      #pragma unroll
      for (int mt = 0; mt < 4; ++mt)
        #pragma unroll
        for (int r = 0; r < 4; ++r) {
          const float a = acc[j][mt][r];
          const ushort h = bf16_rne(a);
          const size_t off = (size_t)(m0 + mt * 16 + quad * 4 + r) * H_ + ncol;
          qh[off] = h;
          ql[off] = bf16_rne(a - bf16_tof(h));
        }
    } else {                                   // k: g in 8..15 -> frag order
      const int hcol = (g - 8) * 16 + l15;
      const int kch  = hcol >> 5;
      const int qdh  = (hcol >> 3) & 3;
      const int jj   = hcol & 7;
      #pragma unroll
      for (int mt = 0; mt < 4; ++mt)
        #pragma unroll
        for (int r = 0; r < 4; ++r) {
          const float a = acc[j][mt][r];
          const int tg = m0 + mt * 16 + quad * 4 + r;
          const int bb = tg >> 11, tl = tg & 2047;
          const size_t ad = FRAGK(bb, tl >> 4, kch, qdh * 16 + (tl & 15)) + jj;
          const ushort h = bf16_rne(a);
          kfh[ad] = h;
          kfl[ad] = bf16_rne(a - bf16_tof(h));
        }
    }
  }
  // ---- epilogue: v (both halves, 64 h-cols each) via LDS transpose ----
  __syncthreads();
  {
    ushort* smT = SM;                          // [64][72] local-h x t
    const int lh = wave * 16 + l15;            // 0..63 (local h col)
    #pragma unroll
    for (int mt = 0; mt < 4; ++mt)
      #pragma unroll
      for (int r = 0; r < 4; ++r)
        smT[lh * 72 + mt * 16 + quad * 4 + r] = bf16_rne(acc[2][mt][r]);
    __syncthreads();
    const int bb = m0 >> 11, t0 = m0 & 2047;
    #pragma unroll
    for (int u = 0; u < 2; ++u) {
      const int c    = u * 256 + tid;          // 512 = 4 lht x 2 ktl x 64 lane
      const int lht  = c >> 7;                 // 0..3
      const int ktl  = (c >> 6) & 1;
      const int lv   = c & 63;
      const int qv   = lv >> 4, l15v = lv & 15;
      *(bf16x8*)(vF + FRAGV(bb, half * 4 + lht, (t0 >> 5) + ktl, lv)) =
          *(const bf16x8*)&smT[(lht * 16 + l15v) * 72 + ktl * 32 + qv * 8];
    }
  }
}

// ---------------------------------------------------------------------------
// Kernel 2: block flash attention, round-12: SWAPPED operands.
//  * S^T = K·Q^T  (A = K-frag, B = Q-frag — same fragment layouts as before,
//    only mfma argument order changes). Output: lane (quad,l15) holds
//    S^T[key = k0 + t*16 + quad*4 + r][q = q0w + l15].
//  * softmax per lane tracks ONE q-row (q=l15): in-register max/sum tree +
//    2 __shfl_xor (16,32) replaces 8 serial DPP chains; 1 mstate/alpha/exp
//    track instead of 4. ~40% VALU cut, much shorter dep chains.
//  * P^T packed in-register (4 u32) -> 2 ds_write_b64 + 1 ds_read_b128
//    (was 8 ds_write_b16).
//  * O^T = V^T·P^T (A = vF-frag as-is, B = packed P^T). Epilogue transposes
//    O^T -> [q][h] via LDS (staging buffers reused post-barrier), so Opart
//    layout and attn_combine are unchanged.
// ---------------------------------------------------------------------------
__global__ __launch_bounds__(256) void attn_flash(
    const ushort* __restrict__ qh, const ushort* __restrict__ ql,
    const ushort* __restrict__ kfh, const ushort* __restrict__ kfl,
    const ushort* __restrict__ vF,
    ushort* __restrict__ Opart, float* __restrict__ mlpart)
{
  const int b    = (int)blockIdx.x & 7;        // %8 -> XCD pin
  const int seg  = (int)blockIdx.x >> 3;
  const int qt   = 31 - (int)blockIdx.y;       // heavy first
  const int q0   = qt * 64;
  const int tid  = threadIdx.x;
  const int wave = tid >> 6, lane = tid & 63;
  const int quad = lane >> 4, l15 = lane & 15;
  const f32x4 z4 = (f32x4){0.f, 0.f, 0.f, 0.f};

  __shared__ __align__(16) ushort SMa[12288];   // Kh|Kl|Vt staging; smO epilogue
  __shared__ __align__(16) unsigned smPw[1280]; // 4 waves x [16 q][20 u32] P^T
  ushort* KhS = SMa;                            // [s(2)][kc(4)][lane][8] linear
  ushort* KlS = SMa + 4096;
  ushort* VtS = SMa + 8192;                     // [ht(8)][lane][8] linear
  unsigned* pw = smPw + wave * 320;

  const int ntiles = 2 * qt + 2;
  const int cnt    = (ntiles + SEG_ - 1) >> 2;
  const int jt0    = seg * cnt;
  const int jt1    = (jt0 + cnt < ntiles) ? (jt0 + cnt) : ntiles;

  const int q0w = q0 + wave * 16;
  const int ntw = ((q0w + 15) >> 5) + 1;
  const size_t pidx = ((size_t)(b * 128 + qt * 4 + wave)) * SEG_ + seg;
  ushort* op = Opart + pidx * 2048;
  float*  ml = mlpart + pidx * 32;

  if (jt0 >= jt1) {                             // block-uniform early exit
    const bf16x8 zz = {0, 0, 0, 0, 0, 0, 0, 0};
    #pragma unroll
    for (int u = 0; u < 4; ++u)
      *(bf16x8*)(op + lane * 32 + u * 8) = zz;
    if (lane < 32) ml[lane] = (lane & 1) ? 0.f : -1e30f;
    return;
  }

  const size_t base = (size_t)b * T_ * H_;

  const ushort* qhp = qh + base + (size_t)(q0w + l15) * H_ + quad * 8;
  const ushort* qlp = ql + base + (size_t)(q0w + l15) * H_ + quad * 8;
  bf16x8 Qh[4], Ql[4];
  #pragma unroll
  for (int c = 0; c < 4; ++c) {
    Qh[c] = *(const bf16x8*)(qhp + c * 32);
    Ql[c] = *(const bf16x8*)(qlp + c * 32);
  }

  f32x4 O[8];                                   // O^T tiles: h=ct*16+quad*4+r, q=l15
  #pragma unroll
  for (int i = 0; i < 8; ++i) O[i] = z4;
  float mst = -1e30f;                           // raw (unscaled) units
  float lst = 0.f;

  bf16x8 rkh[2], rkl[2], rv[2];
  {
    #pragma unroll
    for (int u = 0; u < 2; ++u) {
      const int c = u * 256 + tid;
      rkh[u] = *(const bf16x8*)(kfh + FRAGK(b, 2 * jt0 + (c >> 8), (c >> 6) & 3, c & 63));
      rkl[u] = *(const bf16x8*)(kfl + FRAGK(b, 2 * jt0 + (c >> 8), (c >> 6) & 3, c & 63));
      rv[u]  = *(const bf16x8*)(vF  + FRAGV(b, c >> 6, jt0, c & 63));
    }
  }

  for (int jt = jt0; jt < jt1; ++jt) {
    __syncthreads();
    #pragma unroll
    for (int u = 0; u < 2; ++u) {
      const int c = u * 256 + tid;
      *(bf16x8*)&KhS[c * 8] = rkh[u];
      *(bf16x8*)&KlS[c * 8] = rkl[u];
      *(bf16x8*)&VtS[c * 8] = rv[u];
    }
    __syncthreads();

    if (jt + 1 < jt1) {
      #pragma unroll
      for (int u = 0; u < 2; ++u) {
        const int c = u * 256 + tid;
        rkh[u] = *(const bf16x8*)(kfh + FRAGK(b, 2 * (jt + 1) + (c >> 8), (c >> 6) & 3, c & 63));
        rkl[u] = *(const bf16x8*)(kfl + FRAGK(b, 2 * (jt + 1) + (c >> 8), (c >> 6) & 3, c & 63));
        rv[u]  = *(const bf16x8*)(vF  + FRAGV(b, c >> 6, jt + 1, c & 63));
      }
    }

    if (jt < ntw) {
      const int k0 = jt * 32;
      f32x4 shh0 = z4, shh1 = z4, sx0 = z4, sx1 = z4;
      #pragma unroll
      for (int c = 0; c < 4; ++c) {
        const bf16x8 kh0 = *(const bf16x8*)&KhS[(c * 64 + lane) * 8];
        const bf16x8 kh1 = *(const bf16x8*)&KhS[((4 + c) * 64 + lane) * 8];
        const bf16x8 kl0 = *(const bf16x8*)&KlS[(c * 64 + lane) * 8];
        const bf16x8 kl1 = *(const bf16x8*)&KlS[((4 + c) * 64 + lane) * 8];
        shh0 = mfma16(kh0, Qh[c], shh0);        // A = K, B = Q  (swapped)
        shh1 = mfma16(kh1, Qh[c], shh1);
        sx0  = mfma16(kl0, Qh[c], sx0);
        sx1  = mfma16(kl1, Qh[c], sx1);
        sx0  = mfma16(kh0, Ql[c], sx0);
        sx1  = mfma16(kh1, Ql[c], sx1);
      }

      float r0[4], r1[4];                       // RAW scores, key=k0+t*16+quad*4+r
      #pragma unroll
      for (int r = 0; r < 4; ++r) {
        r0[r] = shh0[r] + sx0[r];
        r1[r] = shh1[r] + sx1[r];
      }
      if (jt == ntw - 1) {                      // causal: mask key > q
        const int base0 = q0w + l15 - k0 - quad * 4;
        #pragma unroll
        for (int r = 0; r < 4; ++r) {
          if (r > base0)      r0[r] = -1e30f;
          if (r > base0 - 16) r1[r] = -1e30f;
        }
      }

      float pm = fmaxf(fmaxf(fmaxf(r0[0], r0[1]), fmaxf(r0[2], r0[3])),
                       fmaxf(fmaxf(r1[0], r1[1]), fmaxf(r1[2], r1[3])));
      pm = fmaxf(pm, __shfl_xor(pm, 16));
      pm = fmaxf(pm, __shfl_xor(pm, 32));

      const float mnew  = fmaxf(mst, pm);
      const float alpha = __expf((mst - mnew) * SCALE_);
      mst = mnew;

      float p0[4], p1[4];
      #pragma unroll
      for (int r = 0; r < 4; ++r) {
        p0[r] = __expf((r0[r] - mnew) * SCALE_);
        p1[r] = __expf((r1[r] - mnew) * SCALE_);
      }
      float sm = ((p0[0] + p0[1]) + (p0[2] + p0[3])) +
                 ((p1[0] + p1[1]) + (p1[2] + p1[3]));
      sm += __shfl_xor(sm, 16);
      sm += __shfl_xor(sm, 32);
      lst = lst * alpha + sm;

      // pack P^T: row q=l15, key-words 2quad..2quad+1 (t0), 8+2quad.. (t1)
      const unsigned w0 = (unsigned)bf16_rne(p0[0]) | ((unsigned)bf16_rne(p0[1]) << 16);
      const unsigned w1 = (unsigned)bf16_rne(p0[2]) | ((unsigned)bf16_rne(p0[3]) << 16);
      const unsigned w2 = (unsigned)bf16_rne(p1[0]) | ((unsigned)bf16_rne(p1[1]) << 16);
      const unsigned w3 = (unsigned)bf16_rne(p1[2]) | ((unsigned)bf16_rne(p1[3]) << 16);
      *(unsigned long long*)&pw[l15 * 20 + 2 * quad] =
          (unsigned long long)w0 | ((unsigned long long)w1 << 32);
      *(unsigned long long*)&pw[l15 * 20 + 8 + 2 * quad] =
          (unsigned long long)w2 | ((unsigned long long)w3 << 32);

      #pragma unroll
      for (int ct = 0; ct < 8; ++ct) {
        O[ct][0] *= alpha; O[ct][1] *= alpha;
        O[ct][2] *= alpha; O[ct][3] *= alpha;
      }
      const bf16x8 pB = *(const bf16x8*)&pw[l15 * 20 + 4 * quad];
      #pragma unroll
      for (int ct = 0; ct < 8; ++ct) {
        const bf16x8 vf = *(const bf16x8*)&VtS[(ct * 64 + lane) * 8];
        O[ct] = mfma16(vf, pB, O[ct]);          // A = V^T, B = P^T (swapped)
      }
    }
  }

  // ---- epilogue: O^T -> [q][h] via LDS transpose (reuse staging) ----
  __syncthreads();                              // all waves done with K/V LDS
  {
    ushort* smO = SMa + wave * 2176;            // [16 q][136] (pad for banks)
    #pragma unroll
    for (int ct = 0; ct < 8; ++ct)
      #pragma unroll
      for (int r = 0; r < 4; ++r)
        smO[l15 * 136 + ct * 16 + quad * 4 + r] = bf16_rne(O[ct][r]);
    #pragma unroll
    for (int u = 0; u < 4; ++u) {
      const int q_ = u * 4 + quad;
      *(bf16x8*)(op + q_ * 128 + l15 * 8) =
          *(const bf16x8*)&smO[q_ * 136 + l15 * 8];
    }
  }
  if (quad == 0) {
    ml[l15 * 2]     = mst * SCALE_;             // scaled units for combine
    ml[l15 * 2 + 1] = lst;
  }
}

// ---------------------------------------------------------------------------
// Kernel 3: combine 4 split-K partials per q-row (unchanged).
// ---------------------------------------------------------------------------
__global__ __launch_bounds__(256) void attn_combine(
    const ushort* __restrict__ Opart, const float* __restrict__ mlpart,
    float* __restrict__ out)
{
  const int idx = blockIdx.x * 256 + threadIdx.x;
  const int c4  = idx & 31;
  const int r   = idx >> 5;
  const int t   = r & 2047;
  const int qt  = t >> 4, r16 = t & 15;
  const size_t pb = ((size_t)((r >> 11) * 128 + qt)) * SEG_;

  float m[SEG_], l[SEG_];
  #pragma unroll
  for (int s = 0; s < SEG_; ++s) {
    m[s] = mlpart[(pb + s) * 32 + r16 * 2];
    l[s] = mlpart[(pb + s) * 32 + r16 * 2 + 1];
  }
  float M = m[0];
  #pragma unroll
  for (int s = 1; s < SEG_; ++s) M = fmaxf(M, m[s]);
  float w[SEG_], L = 0.f;
  #pragma unroll
  for (int s = 0; s < SEG_; ++s) {
    w[s] = __expf(m[s] - M);
    L += l[s] * w[s];
  }
  float4 acc = make_float4(0.f, 0.f, 0.f, 0.f);
  #pragma unroll
  for (int s = 0; s < SEG_; ++s) {
    const ushort4 o = *(const ushort4*)(Opart + (pb + s) * 2048 + r16 * 128 + c4 * 4);
    acc.x += w[s] * bf16_tof(o.x);
    acc.y += w[s] * bf16_tof(o.y);
    acc.z += w[s] * bf16_tof(o.z);
    acc.w += w[s] * bf16_tof(o.w);
  }
  const float inv = 1.0f / L;
  *(float4*)(out + (size_t)r * H_ + c4 * 4) =
      make_float4(acc.x * inv, acc.y * inv, acc.z * inv, acc.w * inv);
}

// ---------------------------------------------------------------------------
extern "C" void kernel_launch(void* const* d_in, const int* in_sizes, int n_in,
                              void* d_out, int out_size, void* d_ws, size_t ws_size,
                              hipStream_t stream) {
  (void)in_sizes; (void)n_in; (void)out_size; (void)ws_size;
  const float* x  = (const float*)d_in[0];
  const float* Wq = (const float*)d_in[1];
  const float* Wk = (const float*)d_in[2];
  const float* Wv = (const float*)d_in[3];
  float* out = (float*)d_out;

  ushort* qhb = (ushort*)d_ws;
  ushort* qlb = qhb + (size_t)M_ * H_;
  ushort* kfh = qlb + (size_t)M_ * H_;
  ushort* kfl = kfh + (size_t)M_ * H_;
  ushort* vFb = kfl + (size_t)M_ * H_;
  ushort* whT = vFb + (size_t)M_ * H_;
  ushort* wlT = whT + (size_t)3 * H_ * E_;
  ushort* Opart = wlT + (size_t)3 * H_ * E_;
  float*  mlpart = (float*)(Opart + (size_t)B_ * 128 * SEG_ * 2048);

  wsplit<<<dim3(192), 256, 0, stream>>>(Wq, Wk, Wv, whT, wlT);
  proj_fused<<<dim3(M_/64, 2), 256, 0, stream>>>(x, whT, wlT,
                                                 qhb, qlb, kfh, kfl, vFb);
  attn_flash<<<dim3(B_*SEG_, 32), 256, 0, stream>>>(qhb, qlb, kfh, kfl, vFb,
                                                    Opart, mlpart);
  attn_combine<<<dim3(2048), 256, 0, stream>>>(Opart, mlpart, out);
}

// Round 6
// 169.980 us; speedup vs baseline: 1.1170x; 1.0024x over previous
//
#include <hip/hip_runtime.h>
#include <hip/hip_bf16.h>
#include <math.h>

#define B_ 8
#define T_ 2048
#define E_ 1024
#define H_ 128
#define M_ (B_*T_)              // 16384
#define SCALE_ 45.25483399593904f   // sqrt(2048) per reference
#define SEG_ 4                      // key-range split factor for attention

typedef __attribute__((ext_vector_type(8))) short bf16x8;
typedef __attribute__((ext_vector_type(4))) float f32x4;

#define mfma16(A, Bv, C) __builtin_amdgcn_mfma_f32_16x16x32_bf16((A), (Bv), (C), 0, 0, 0)

// ---- fragment-order flat indices (ushort elements) -------------------------
// lane = quad*16 + l15 throughout.
// W-frag (proj B operand): g = mat*8+nt (0..23), kc = k/32 (0..31);
//   element (n = (g&7)*16 + l15, k = kc*32 + quad*8 + j)
#define FRAGW(g, kc, lane)  ((((size_t)(g)*32 + (kc))*64 + (lane))*8)
// K-frag (attn QK A operand, swapped): kt16 = key/16 (0..127), kc = h/32 (0..3);
//   element (key = kt16*16 + l15, h = kc*32 + quad*8 + j)
#define FRAGK(b, kt16, kc, lane) (((((size_t)(b)*128 + (kt16))*4 + (kc))*64 + (lane))*8)
// V-frag (attn PV A operand, swapped): ht = h/16 (0..7), kt32 = key/32 (0..63);
//   element (h = ht*16 + l15, key = kt32*32 + quad*8 + j)
#define FRAGV(b, ht, kt32, lane) (((((size_t)(b)*8 + (ht))*64 + (kt32))*64 + (lane))*8)

__device__ __forceinline__ ushort bf16_rne(float f) {
  unsigned u = __float_as_uint(f);
  u += 0x7fffu + ((u >> 16) & 1u);
  return (ushort)(u >> 16);
}
__device__ __forceinline__ float bf16_tof(ushort h) {
  return __uint_as_float(((unsigned)h) << 16);
}

// LDS-only barrier: drain DS ops (cross-wave LDS dependency) but leave
// register-destined global prefetches (vmcnt) in flight across the barrier.
__device__ __forceinline__ void lds_barrier() {
  asm volatile("s_waitcnt lgkmcnt(0)" ::: "memory");
  __builtin_amdgcn_s_barrier();
}

// ---------------------------------------------------------------------------
// Kernel 0: split W -> whT/wlT bf16 in PROJ-B FRAGMENT ORDER. (unchanged)
// ---------------------------------------------------------------------------
__global__ __launch_bounds__(256) void wsplit(
    const float* __restrict__ Wq, const float* __restrict__ Wk,
    const float* __restrict__ Wv,
    ushort* __restrict__ whT, ushort* __restrict__ wlT)
{
  const int idx  = blockIdx.x * 256 + threadIdx.x;  // 0..49151
  const int mat  = idx >> 14;                       // 16384 chunks per mat
  const int rem  = idx & 16383;
  const int nt   = rem >> 11;                       // 0..7
  const int kc   = (rem >> 6) & 31;                 // 0..31
  const int lane = rem & 63;
  const int quad = lane >> 4, l15 = lane & 15;
  const float* W = (mat == 0) ? Wq : (mat == 1) ? Wk : Wv;
  const int n  = nt * 16 + l15;
  const int k0 = kc * 32 + quad * 8;
  bf16x8 hv, lv;
  #pragma unroll
  for (int j = 0; j < 8; ++j) {
    const float f = W[(size_t)(k0 + j) * H_ + n];
    const ushort h = bf16_rne(f);
    hv[j] = (short)h;
    lv[j] = (short)bf16_rne(f - bf16_tof(h));
  }
  *(bf16x8*)(whT + (size_t)idx * 8) = hv;   // == FRAGW(mat*8+nt, kc, lane)
  *(bf16x8*)(wlT + (size_t)idx * 8) = lv;
}

// ---------------------------------------------------------------------------
// Kernel 1: fused QKV projection, round-13 (= round-11 + LDS swizzle + setprio):
//  * A-frag chunks XOR-swizzled: chunk = (rowhi*4+koff)*16 + (rowlo^koff).
//    Kills the 4-way ds_write_b128 bank conflict (lanes 0-3 previously hit
//    one 4-bank group); reads remain conflict-free. Pure address permutation.
//  * s_setprio(1) around MFMA clusters (2 independent blocks/CU -> wave
//    role diversity, T5 regime).
// ---------------------------------------------------------------------------
#define CVT8W(F0, F1, DSTOFF) do {                                            \
    const float f_[8] = {(F0).x, (F0).y, (F0).z, (F0).w,                      \
                         (F1).x, (F1).y, (F1).z, (F1).w};                     \
    bf16x8 hv_, lv_;                                                          \
    _Pragma("unroll")                                                         \
    for (int jj_ = 0; jj_ < 8; ++jj_) {                                       \
      const ushort h_ = bf16_rne(f_[jj_]);                                    \
      hv_[jj_] = (short)h_;                                                   \
      lv_[jj_] = (short)bf16_rne(f_[jj_] - bf16_tof(h_));                     \
    }                                                                         \
    *(bf16x8*)&SM[(DSTOFF) + ca * 8] = hv_;                                   \
    *(bf16x8*)&SM[(DSTOFF) + 2048 + ca * 8] = lv_;                            \
  } while (0)

#define AFRAG(CUR, HALFOFF, MT) \
    (*(const bf16x8*)&SM[(CUR)*8192 + (HALFOFF) + \
        (((MT)*4 + quad)*16 + (l15 ^ quad))*8])

#define PSTEP4(S, CUR, NXT, BHC, BLC, BHN, BLN) do {                          \
    bf16x8 ah_[4], al_[4];                                                    \
    _Pragma("unroll")                                                         \
    for (int mt_ = 0; mt_ < 4; ++mt_) {                                       \
      ah_[mt_] = AFRAG(CUR, 0,    mt_);                                       \
      al_[mt_] = AFRAG(CUR, 2048, mt_);                                       \
    }                                                                         \
    if ((S) + 1 < 16) {                                                       \
      _Pragma("unroll")                                                       \
      for (int kch_ = 0; kch_ < 2; ++kch_) {                                  \
        const int kcn_ = 2*((S)+1) + kch_;                                    \
        BHN[kch_*3+0] = *(const bf16x8*)(whT + FRAGW(gq,     kcn_, lane));    \
        BHN[kch_*3+1] = *(const bf16x8*)(whT + FRAGW(gq + 4, kcn_, lane));    \
        BHN[kch_*3+2] = *(const bf16x8*)(whT + FRAGW(gv,     kcn_, lane));    \
        BLN[kch_*2+0] = *(const bf16x8*)(wlT + FRAGW(gq,     kcn_, lane));    \
        BLN[kch_*2+1] = *(const bf16x8*)(wlT + FRAGW(gq + 4, kcn_, lane));    \
      }                                                                       \
    }                                                                         \
    float4 nx0_, nx1_, nx2_, nx3_;                                            \
    if ((S) + 2 < 16) {                                                       \
      nx0_ = *(const float4*)(xrow + 64*((S)+2));                             \
      nx1_ = *(const float4*)(xrow + 64*((S)+2) + 4);                         \
      nx2_ = *(const float4*)(xrow + 64*((S)+2) + 32);                        \
      nx3_ = *(const float4*)(xrow + 64*((S)+2) + 36);                        \
    } else { nx0_ = xf0; nx1_ = xf1; nx2_ = xf2; nx3_ = xf3; }                \
    /* MFMA kch0 (kc = 2S) */                                                 \
    __builtin_amdgcn_s_setprio(1);                                            \
    _Pragma("unroll")                                                         \
    for (int mt_ = 0; mt_ < 4; ++mt_) {                                       \
      acc[0][mt_] = mfma16(ah_[mt_], BHC[0], acc[0][mt_]);                    \
      acc[0][mt_] = mfma16(ah_[mt_], BLC[0], acc[0][mt_]);                    \
      acc[0][mt_] = mfma16(al_[mt_], BHC[0], acc[0][mt_]);                    \
      acc[1][mt_] = mfma16(ah_[mt_], BHC[1], acc[1][mt_]);                    \
      acc[1][mt_] = mfma16(ah_[mt_], BLC[1], acc[1][mt_]);                    \
      acc[1][mt_] = mfma16(al_[mt_], BHC[1], acc[1][mt_]);                    \
      acc[2][mt_] = mfma16(ah_[mt_], BHC[2], acc[2][mt_]);                    \
    }                                                                         \
    __builtin_amdgcn_s_setprio(0);                                            \
    /* stage A(S+1) into NXT buffer */                                        \
    if ((S) + 1 < 16) {                                                       \
      CVT8W(xf0, xf1, (NXT)*8192);                                            \
      CVT8W(xf2, xf3, (NXT)*8192 + 4096);                                     \
    }                                                                         \
    /* A-frags kch1 (kc = 2S+1) */                                            \
    _Pragma("unroll")                                                         \
    for (int mt_ = 0; mt_ < 4; ++mt_) {                                       \
      ah_[mt_] = AFRAG(CUR, 4096, mt_);                                       \
      al_[mt_] = AFRAG(CUR, 6144, mt_);                                       \
    }                                                                         \
    __builtin_amdgcn_s_setprio(1);                                            \
    _Pragma("unroll")                                                         \
    for (int mt_ = 0; mt_ < 4; ++mt_) {                                       \
      acc[0][mt_] = mfma16(ah_[mt_], BHC[3], acc[0][mt_]);                    \
      acc[0][mt_] = mfma16(ah_[mt_], BLC[2], acc[0][mt_]);                    \
      acc[0][mt_] = mfma16(al_[mt_], BHC[3], acc[0][mt_]);                    \
      acc[1][mt_] = mfma16(ah_[mt_], BHC[4], acc[1][mt_]);                    \
      acc[1][mt_] = mfma16(ah_[mt_], BLC[3], acc[1][mt_]);                    \
      acc[1][mt_] = mfma16(al_[mt_], BHC[4], acc[1][mt_]);                    \
      acc[2][mt_] = mfma16(ah_[mt_], BHC[5], acc[2][mt_]);                    \
    }                                                                         \
    __builtin_amdgcn_s_setprio(0);                                            \
    xf0 = nx0_; xf1 = nx1_; xf2 = nx2_; xf3 = nx3_;                           \
    lds_barrier();                                                            \
  } while (0)

__global__ __launch_bounds__(256, 2) void proj_fused(
    const float* __restrict__ x,
    const ushort* __restrict__ whT, const ushort* __restrict__ wlT,
    ushort* __restrict__ qh, ushort* __restrict__ ql,
    ushort* __restrict__ kfh, ushort* __restrict__ kfl,
    ushort* __restrict__ vF)
{
  const int m0   = blockIdx.x * 64;
  const int half = blockIdx.y;
  const int tid  = threadIdx.x;
  const int wave = tid >> 6, lane = tid & 63;
  const int quad = lane >> 4, l15 = lane & 15;

  __shared__ __align__(16) ushort SM[16384]; // 32KB: 2 bufs x [Ah0|Al0|Ah1|Al1]

  f32x4 acc[3][4];
  #pragma unroll
  for (int j = 0; j < 3; ++j)
    #pragma unroll
    for (int mt = 0; mt < 4; ++mt) acc[j][mt] = (f32x4){0.f, 0.f, 0.f, 0.f};

  const int arow  = tid >> 2;          // 0..63
  const int akoff = (tid & 3) * 8;     // 0,8,16,24
  // XOR-swizzled A chunk: (rowhi*4 + koff)*16 + (rowlo ^ koff)
  const int ca    = ((arow >> 4) * 4 + (tid & 3)) * 16
                    + ((arow & 15) ^ (tid & 3));
  const int gq    = half * 8 + wave;   // qk tiles: gq (j=0), gq+4 (j=1)
  const int gv    = 16 + half * 4 + wave;  // v tile (j=2)

  const float* xrow = x + (size_t)(m0 + arow) * E_ + akoff;

  float4 xf0, xf1, xf2, xf3;       // x floats for step S+1 (kc 2S+2, 2S+3)
  bf16x8 bhA[6], blA[4], bhB[6], blB[4];

  // ---- prologue: A(step0: kc0,kc1) -> buf0; prefetch xf(step1), B(step0) --
  {
    const float4 a0 = *(const float4*)(xrow);
    const float4 a1 = *(const float4*)(xrow + 4);
    const float4 a2 = *(const float4*)(xrow + 32);
    const float4 a3 = *(const float4*)(xrow + 36);
    CVT8W(a0, a1, 0);
    CVT8W(a2, a3, 4096);
    xf0 = *(const float4*)(xrow + 64);
    xf1 = *(const float4*)(xrow + 68);
    xf2 = *(const float4*)(xrow + 96);
    xf3 = *(const float4*)(xrow + 100);
    #pragma unroll
    for (int kch = 0; kch < 2; ++kch) {
      bhA[kch*3+0] = *(const bf16x8*)(whT + FRAGW(gq,     kch, lane));
      bhA[kch*3+1] = *(const bf16x8*)(whT + FRAGW(gq + 4, kch, lane));
      bhA[kch*3+2] = *(const bf16x8*)(whT + FRAGW(gv,     kch, lane));
      blA[kch*2+0] = *(const bf16x8*)(wlT + FRAGW(gq,     kch, lane));
      blA[kch*2+1] = *(const bf16x8*)(wlT + FRAGW(gq + 4, kch, lane));
    }
  }
  lds_barrier();

  int s = 0;
  while (true) {
    PSTEP4(s, 0, 1, bhA, blA, bhB, blB); if (++s == 16) break;
    PSTEP4(s, 1, 0, bhB, blB, bhA, blA); if (++s == 16) break;
  }

  // ---- epilogue: j<2 -> q (half0) in [t][h] / k (half1) in frag order ----
  #pragma unroll
  for (int j = 0; j < 2; ++j) {
    const int g = gq + 4 * j;
    if (half == 0) {                           // q: g in 0..7
      const int ncol = g * 16 + l15;
      #pragma unroll
      for (int mt = 0; mt < 4; ++mt)
        #pragma unroll
        for (int r = 0; r < 4; ++r) {
          const float a = acc[j][mt][r];
          const ushort h = bf16_rne(a);
          const size_t off = (size_t)(m0 + mt * 16 + quad * 4 + r) * H_ + ncol;
          qh[off] = h;
          ql[off] = bf16_rne(a - bf16_tof(h));
        }
    } else {                                   // k: g in 8..15 -> frag order
      const int hcol = (g - 8) * 16 + l15;
      const int kch  = hcol >> 5;
      const int qdh  = (hcol >> 3) & 3;
      const int jj   = hcol & 7;
      #pragma unroll
      for (int mt = 0; mt < 4; ++mt)
        #pragma unroll
        for (int r = 0; r < 4; ++r) {
          const float a = acc[j][mt][r];
          const int tg = m0 + mt * 16 + quad * 4 + r;
          const int bb = tg >> 11, tl = tg & 2047;
          const size_t ad = FRAGK(bb, tl >> 4, kch, qdh * 16 + (tl & 15)) + jj;
          const ushort h = bf16_rne(a);
          kfh[ad] = h;
          kfl[ad] = bf16_rne(a - bf16_tof(h));
        }
    }
  }
  // ---- epilogue: v (both halves, 64 h-cols each) via LDS transpose ----
  __syncthreads();
  {
    ushort* smT = SM;                          // [64][72] local-h x t
    const int lh = wave * 16 + l15;            // 0..63 (local h col)
    #pragma unroll
    for (int mt = 0; mt < 4; ++mt)
      #pragma unroll
      for (int r = 0; r < 4; ++r)
        smT[lh * 72 + mt * 16 + quad * 4 + r] = bf16_rne(acc[2][mt][r]);
    __syncthreads();
    const int bb = m0 >> 11, t0 = m0 & 2047;
    #pragma unroll
    for (int u = 0; u < 2; ++u) {
      const int c    = u * 256 + tid;          // 512 = 4 lht x 2 ktl x 64 lane
      const int lht  = c >> 7;                 // 0..3
      const int ktl  = (c >> 6) & 1;
      const int lv   = c & 63;
      const int qv   = lv >> 4, l15v = lv & 15;
      *(bf16x8*)(vF + FRAGV(bb, half * 4 + lht, (t0 >> 5) + ktl, lv)) =
          *(const bf16x8*)&smT[(lht * 16 + l15v) * 72 + ktl * 32 + qv * 8];
    }
  }
}

// ---------------------------------------------------------------------------
// Kernel 2: block flash attention (round-12 swapped version, unchanged).
// ---------------------------------------------------------------------------
__global__ __launch_bounds__(256) void attn_flash(
    const ushort* __restrict__ qh, const ushort* __restrict__ ql,
    const ushort* __restrict__ kfh, const ushort* __restrict__ kfl,
    const ushort* __restrict__ vF,
    ushort* __restrict__ Opart, float* __restrict__ mlpart)
{
  const int b    = (int)blockIdx.x & 7;        // %8 -> XCD pin
  const int seg  = (int)blockIdx.x >> 3;
  const int qt   = 31 - (int)blockIdx.y;       // heavy first
  const int q0   = qt * 64;
  const int tid  = threadIdx.x;
  const int wave = tid >> 6, lane = tid & 63;
  const int quad = lane >> 4, l15 = lane & 15;
  const f32x4 z4 = (f32x4){0.f, 0.f, 0.f, 0.f};

  __shared__ __align__(16) ushort SMa[12288];   // Kh|Kl|Vt staging; smO epilogue
  __shared__ __align__(16) unsigned smPw[1280]; // 4 waves x [16 q][20 u32] P^T
  ushort* KhS = SMa;                            // [s(2)][kc(4)][lane][8] linear
  ushort* KlS = SMa + 4096;
  ushort* VtS = SMa + 8192;                     // [ht(8)][lane][8] linear
  unsigned* pw = smPw + wave * 320;

  const int ntiles = 2 * qt + 2;
  const int cnt    = (ntiles + SEG_ - 1) >> 2;
  const int jt0    = seg * cnt;
  const int jt1    = (jt0 + cnt < ntiles) ? (jt0 + cnt) : ntiles;

  const int q0w = q0 + wave * 16;
  const int ntw = ((q0w + 15) >> 5) + 1;
  const size_t pidx = ((size_t)(b * 128 + qt * 4 + wave)) * SEG_ + seg;
  ushort* op = Opart + pidx * 2048;
  float*  ml = mlpart + pidx * 32;

  if (jt0 >= jt1) {                             // block-uniform early exit
    const bf16x8 zz = {0, 0, 0, 0, 0, 0, 0, 0};
    #pragma unroll
    for (int u = 0; u < 4; ++u)
      *(bf16x8*)(op + lane * 32 + u * 8) = zz;
    if (lane < 32) ml[lane] = (lane & 1) ? 0.f : -1e30f;
    return;
  }

  const size_t base = (size_t)b * T_ * H_;

  const ushort* qhp = qh + base + (size_t)(q0w + l15) * H_ + quad * 8;
  const ushort* qlp = ql + base + (size_t)(q0w + l15) * H_ + quad * 8;
  bf16x8 Qh[4], Ql[4];
  #pragma unroll
  for (int c = 0; c < 4; ++c) {
    Qh[c] = *(const bf16x8*)(qhp + c * 32);
    Ql[c] = *(const bf16x8*)(qlp + c * 32);
  }

  f32x4 O[8];                                   // O^T tiles: h=ct*16+quad*4+r, q=l15
  #pragma unroll
  for (int i = 0; i < 8; ++i) O[i] = z4;
  float mst = -1e30f;                           // raw (unscaled) units
  float lst = 0.f;

  bf16x8 rkh[2], rkl[2], rv[2];
  {
    #pragma unroll
    for (int u = 0; u < 2; ++u) {
      const int c = u * 256 + tid;
      rkh[u] = *(const bf16x8*)(kfh + FRAGK(b, 2 * jt0 + (c >> 8), (c >> 6) & 3, c & 63));
      rkl[u] = *(const bf16x8*)(kfl + FRAGK(b, 2 * jt0 + (c >> 8), (c >> 6) & 3, c & 63));
      rv[u]  = *(const bf16x8*)(vF  + FRAGV(b, c >> 6, jt0, c & 63));
    }
  }

  for (int jt = jt0; jt < jt1; ++jt) {
    __syncthreads();
    #pragma unroll
    for (int u = 0; u < 2; ++u) {
      const int c = u * 256 + tid;
      *(bf16x8*)&KhS[c * 8] = rkh[u];
      *(bf16x8*)&KlS[c * 8] = rkl[u];
      *(bf16x8*)&VtS[c * 8] = rv[u];
    }
    __syncthreads();

    if (jt + 1 < jt1) {
      #pragma unroll
      for (int u = 0; u < 2; ++u) {
        const int c = u * 256 + tid;
        rkh[u] = *(const bf16x8*)(kfh + FRAGK(b, 2 * (jt + 1) + (c >> 8), (c >> 6) & 3, c & 63));
        rkl[u] = *(const bf16x8*)(kfl + FRAGK(b, 2 * (jt + 1) + (c >> 8), (c >> 6) & 3, c & 63));
        rv[u]  = *(const bf16x8*)(vF  + FRAGV(b, c >> 6, jt + 1, c & 63));
      }
    }

    if (jt < ntw) {
      const int k0 = jt * 32;
      f32x4 shh0 = z4, shh1 = z4, sx0 = z4, sx1 = z4;
      #pragma unroll
      for (int c = 0; c < 4; ++c) {
        const bf16x8 kh0 = *(const bf16x8*)&KhS[(c * 64 + lane) * 8];
        const bf16x8 kh1 = *(const bf16x8*)&KhS[((4 + c) * 64 + lane) * 8];
        const bf16x8 kl0 = *(const bf16x8*)&KlS[(c * 64 + lane) * 8];
        const bf16x8 kl1 = *(const bf16x8*)&KlS[((4 + c) * 64 + lane) * 8];
        shh0 = mfma16(kh0, Qh[c], shh0);        // A = K, B = Q  (swapped)
        shh1 = mfma16(kh1, Qh[c], shh1);
        sx0  = mfma16(kl0, Qh[c], sx0);
        sx1  = mfma16(kl1, Qh[c], sx1);
        sx0  = mfma16(kh0, Ql[c], sx0);
        sx1  = mfma16(kh1, Ql[c], sx1);
      }

      float r0[4], r1[4];                       // RAW scores, key=k0+t*16+quad*4+r
      #pragma unroll
      for (int r = 0; r < 4; ++r) {
        r0[r] = shh0[r] + sx0[r];
        r1[r] = shh1[r] + sx1[r];
      }
      if (jt == ntw - 1) {                      // causal: mask key > q
        const int base0 = q0w + l15 - k0 - quad * 4;
        #pragma unroll
        for (int r = 0; r < 4; ++r) {
          if (r > base0)      r0[r] = -1e30f;
          if (r > base0 - 16) r1[r] = -1e30f;
        }
      }

      float pm = fmaxf(fmaxf(fmaxf(r0[0], r0[1]), fmaxf(r0[2], r0[3])),
                       fmaxf(fmaxf(r1[0], r1[1]), fmaxf(r1[2], r1[3])));
      pm = fmaxf(pm, __shfl_xor(pm, 16));
      pm = fmaxf(pm, __shfl_xor(pm, 32));

      const float mnew  = fmaxf(mst, pm);
      const float alpha = __expf((mst - mnew) * SCALE_);
      mst = mnew;

      float p0[4], p1[4];
      #pragma unroll
      for (int r = 0; r < 4; ++r) {
        p0[r] = __expf((r0[r] - mnew) * SCALE_);
        p1[r] = __expf((r1[r] - mnew) * SCALE_);
      }
      float sm = ((p0[0] + p0[1]) + (p0[2] + p0[3])) +
                 ((p1[0] + p1[1]) + (p1[2] + p1[3]));
      sm += __shfl_xor(sm, 16);
      sm += __shfl_xor(sm, 32);
      lst = lst * alpha + sm;

      // pack P^T: row q=l15, key-words 2quad..2quad+1 (t0), 8+2quad.. (t1)
      const unsigned w0 = (unsigned)bf16_rne(p0[0]) | ((unsigned)bf16_rne(p0[1]) << 16);
      const unsigned w1 = (unsigned)bf16_rne(p0[2]) | ((unsigned)bf16_rne(p0[3]) << 16);
      const unsigned w2 = (unsigned)bf16_rne(p1[0]) | ((unsigned)bf16_rne(p1[1]) << 16);
      const unsigned w3 = (unsigned)bf16_rne(p1[2]) | ((unsigned)bf16_rne(p1[3]) << 16);
      *(unsigned long long*)&pw[l15 * 20 + 2 * quad] =
          (unsigned long long)w0 | ((unsigned long long)w1 << 32);
      *(unsigned long long*)&pw[l15 * 20 + 8 + 2 * quad] =
          (unsigned long long)w2 | ((unsigned long long)w3 << 32);

      #pragma unroll
      for (int ct = 0; ct < 8; ++ct) {
        O[ct][0] *= alpha; O[ct][1] *= alpha;
        O[ct][2] *= alpha; O[ct][3] *= alpha;
      }
      const bf16x8 pB = *(const bf16x8*)&pw[l15 * 20 + 4 * quad];
      #pragma unroll
      for (int ct = 0; ct < 8; ++ct) {
        const bf16x8 vf = *(const bf16x8*)&VtS[(ct * 64 + lane) * 8];
        O[ct] = mfma16(vf, pB, O[ct]);          // A = V^T, B = P^T (swapped)
      }
    }
  }

  // ---- epilogue: O^T -> [q][h] via LDS transpose (reuse staging) ----
  __syncthreads();                              // all waves done with K/V LDS
  {
    ushort* smO = SMa + wave * 2176;            // [16 q][136] (pad for banks)
    #pragma unroll
    for (int ct = 0; ct < 8; ++ct)
      #pragma unroll
      for (int r = 0; r < 4; ++r)
        smO[l15 * 136 + ct * 16 + quad * 4 + r] = bf16_rne(O[ct][r]);
    #pragma unroll
    for (int u = 0; u < 4; ++u) {
      const int q_ = u * 4 + quad;
      *(bf16x8*)(op + q_ * 128 + l15 * 8) =
          *(const bf16x8*)&smO[q_ * 136 + l15 * 8];
    }
  }
  if (quad == 0) {
    ml[l15 * 2]     = mst * SCALE_;             // scaled units for combine
    ml[l15 * 2 + 1] = lst;
  }
}

// ---------------------------------------------------------------------------
// Kernel 3: combine 4 split-K partials per q-row (unchanged).
// ---------------------------------------------------------------------------
__global__ __launch_bounds__(256) void attn_combine(
    const ushort* __restrict__ Opart, const float* __restrict__ mlpart,
    float* __restrict__ out)
{
  const int idx = blockIdx.x * 256 + threadIdx.x;
  const int c4  = idx & 31;
  const int r   = idx >> 5;
  const int t   = r & 2047;
  const int qt  = t >> 4, r16 = t & 15;
  const size_t pb = ((size_t)((r >> 11) * 128 + qt)) * SEG_;

  float m[SEG_], l[SEG_];
  #pragma unroll
  for (int s = 0; s < SEG_; ++s) {
    m[s] = mlpart[(pb + s) * 32 + r16 * 2];
    l[s] = mlpart[(pb + s) * 32 + r16 * 2 + 1];
  }
  float M = m[0];
  #pragma unroll
  for (int s = 1; s < SEG_; ++s) M = fmaxf(M, m[s]);
  float w[SEG_], L = 0.f;
  #pragma unroll
  for (int s = 0; s < SEG_; ++s) {
    w[s] = __expf(m[s] - M);
    L += l[s] * w[s];
  }
  float4 acc = make_float4(0.f, 0.f, 0.f, 0.f);
  #pragma unroll
  for (int s = 0; s < SEG_; ++s) {
    const ushort4 o = *(const ushort4*)(Opart + (pb + s) * 2048 + r16 * 128 + c4 * 4);
    acc.x += w[s] * bf16_tof(o.x);
    acc.y += w[s] * bf16_tof(o.y);
    acc.z += w[s] * bf16_tof(o.z);
    acc.w += w[s] * bf16_tof(o.w);
  }
  const float inv = 1.0f / L;
  *(float4*)(out + (size_t)r * H_ + c4 * 4) =
      make_float4(acc.x * inv, acc.y * inv, acc.z * inv, acc.w * inv);
}

// ---------------------------------------------------------------------------
extern "C" void kernel_launch(void* const* d_in, const int* in_sizes, int n_in,
                              void* d_out, int out_size, void* d_ws, size_t ws_size,
                              hipStream_t stream) {
  (void)in_sizes; (void)n_in; (void)out_size; (void)ws_size;
  const float* x  = (const float*)d_in[0];
  const float* Wq = (const float*)d_in[1];
  const float* Wk = (const float*)d_in[2];
  const float* Wv = (const float*)d_in[3];
  float* out = (float*)d_out;

  ushort* qhb = (ushort*)d_ws;
  ushort* qlb = qhb + (size_t)M_ * H_;
  ushort* kfh = qlb + (size_t)M_ * H_;
  ushort* kfl = kfh + (size_t)M_ * H_;
  ushort* vFb = kfl + (size_t)M_ * H_;
  ushort* whT = vFb + (size_t)M_ * H_;
  ushort* wlT = whT + (size_t)3 * H_ * E_;
  ushort* Opart = wlT + (size_t)3 * H_ * E_;
  float*  mlpart = (float*)(Opart + (size_t)B_ * 128 * SEG_ * 2048);

  wsplit<<<dim3(192), 256, 0, stream>>>(Wq, Wk, Wv, whT, wlT);
  proj_fused<<<dim3(M_/64, 2), 256, 0, stream>>>(x, whT, wlT,
                                                 qhb, qlb, kfh, kfl, vFb);
  attn_flash<<<dim3(B_*SEG_, 32), 256, 0, stream>>>(qhb, qlb, kfh, kfl, vFb,
                                                    Opart, mlpart);
  attn_combine<<<dim3(2048), 256, 0, stream>>>(Opart, mlpart, out);
}